// Round 11
// baseline (488.299 us; speedup 1.0000x reference)
//
#include <hip/hip_runtime.h>

#define NN 50000
#define NE 1600000
#define DD 64
#define NGRAPH 64
#define DOUT 32
#define DELTA_F 2.5749f
#define BN_EPS_F 1e-5f

typedef unsigned short ushort;
typedef __attribute__((ext_vector_type(8))) short short8;
typedef __attribute__((ext_vector_type(4))) float floatx4;

static __device__ __forceinline__ float blo(unsigned u) {
    return __uint_as_float(u << 16);
}
static __device__ __forceinline__ float bhi(unsigned u) {
    return __uint_as_float(u & 0xFFFF0000u);
}
static __device__ __forceinline__ float bu2f(ushort u) {
    return __uint_as_float(((unsigned)u) << 16);
}
static __device__ __forceinline__ ushort f2bu(float f) {
    unsigned u = __float_as_uint(f);
    unsigned r = (u + 0x7FFF + ((u >> 16) & 1)) >> 16;   // round-to-nearest-even
    return (ushort)r;
}
static __device__ __forceinline__ unsigned pk(float a, float b) {
    return ((unsigned)f2bu(b) << 16) | (unsigned)f2bu(a);
}

// ---------------- prep: init + x->bf16 + weight prep (fused, 1 launch) ----------------
// Wb: bf16 MFMA B-fragments (mlp GEMM), per layer 4 chunks of 16384:
//   c=0: g=0 (hi), c=1: g=1 hi, c=2: g=1 lo (w - f32(hi)), c=3: g=2 (hi)
// Wsb: bf16 MFMA B-frags for Lin1/Lin2 (64x64), per layer 16384:
//   [lin 2][hl 2][kb 2][t 4][lane 64][j 8]
__global__ void k_prep(const float* __restrict__ x, ushort* __restrict__ XH,
                       const float* __restrict__ w0, const float* __restrict__ w1,
                       const float* __restrict__ w2,
                       const float* __restrict__ a0, const float* __restrict__ a1,
                       const float* __restrict__ a2, const float* __restrict__ a3,
                       const float* __restrict__ a4, const float* __restrict__ a5,
                       ushort* __restrict__ Wb, ushort* __restrict__ Wsb,
                       int* __restrict__ counts, float* __restrict__ bnstat,
                       float* __restrict__ gpool) {
    int i = blockIdx.x * 256 + threadIdx.x;
    if (i < NN) counts[i] = 0;
    if (i < 384) bnstat[i] = 0.f;
    if (i < NGRAPH * DD) gpool[i] = 0.f;
    if (i < NN * 16) {
        float4 v = *(const float4*)(x + (size_t)i * 4);
        ushort4 h;
        h.x = f2bu(v.x); h.y = f2bu(v.y); h.z = f2bu(v.z); h.w = f2bu(v.w);
        *(ushort4*)(XH + (size_t)i * 4) = h;
    }
    if (i < 3 * 65536) {
        int layer = i / 65536, r = i % 65536;
        const float* w = (layer == 0) ? w0 : ((layer == 1) ? w1 : w2);
        int c = r / 16384, r2 = r % 16384;
        int kb = r2 >> 11, r3 = r2 & 2047;
        int t = r3 >> 9, r4 = r3 & 511;
        int l = r4 >> 3, j = r4 & 7;
        int k = kb * 32 + (l >> 4) * 8 + j;
        int o = t * 16 + (l & 15);
        int g = (c == 0) ? 0 : ((c == 3) ? 2 : 1);
        float wv = w[o * 768 + g * 256 + k];
        ushort h = f2bu(wv);
        Wb[i] = (c == 2) ? f2bu(wv - bu2f(h)) : h;
    } else if (i < 3 * 65536 + 3 * 16384) {
        int i2 = i - 3 * 65536;
        int layer = i2 / 16384, r = i2 % 16384;
        int lin = r >> 13, r2 = r & 8191;
        int hl = r2 >> 12, r3 = r2 & 4095;
        int kb = r3 >> 11, r4 = r3 & 2047;
        int t = r4 >> 9, r5 = r4 & 511;
        int l = r5 >> 3, j = r5 & 7;
        int k = kb * 32 + (l >> 4) * 8 + j;
        int o = t * 16 + (l & 15);
        const float* w = (lin == 0)
            ? ((layer == 0) ? a0 : (layer == 1) ? a2 : a4)
            : ((layer == 0) ? a1 : (layer == 1) ? a3 : a5);
        float wv = w[o * 64 + k];
        ushort h = f2bu(wv);
        Wsb[i2] = hl ? f2bu(wv - bu2f(h)) : h;
    }
}

// ---------------- CSR build (rank/scan/place — single atomic pass, int4 loads) --------
__global__ void k_rank(const int* __restrict__ dst, int* __restrict__ counts,
                       int* __restrict__ rank) {
    int i = blockIdx.x * 256 + threadIdx.x;
    if (i < NE / 4) {
        int4 d = ((const int4*)dst)[i];
        int4 r;
        r.x = atomicAdd(&counts[d.x], 1);
        r.y = atomicAdd(&counts[d.y], 1);
        r.z = atomicAdd(&counts[d.z], 1);
        r.w = atomicAdd(&counts[d.w], 1);
        ((int4*)rank)[i] = r;
    }
}

__global__ void k_scan_a(const int* __restrict__ counts, int* __restrict__ blockSums) {
    __shared__ int red[256];
    int tid = threadIdx.x;
    int gid = blockIdx.x * 256 + tid;
    int v = (gid < NN) ? counts[gid] : 0;
    red[tid] = v;
    __syncthreads();
    for (int s = 128; s > 0; s >>= 1) {
        if (tid < s) red[tid] += red[tid + s];
        __syncthreads();
    }
    if (tid == 0) blockSums[blockIdx.x] = red[0];
}

// + gcnt via binary search over sorted batch (zero atomics, no init needed)
__global__ void k_scan_b(const int* __restrict__ blockSums, int* __restrict__ blockBase,
                         const int* __restrict__ batch, int* __restrict__ gcnt) {
    __shared__ int sh[256];
    int tid = threadIdx.x;
    int v = (tid < 196) ? blockSums[tid] : 0;
    sh[tid] = v;
    __syncthreads();
    for (int off = 1; off < 256; off <<= 1) {
        int t = (tid >= off) ? sh[tid - off] : 0;
        __syncthreads();
        sh[tid] += t;
        __syncthreads();
    }
    blockBase[tid] = sh[tid] - v;  // exclusive
    if (tid < NGRAPH) {
        auto lb = [&](int g) {
            int lo = 0, hi = NN;
            while (lo < hi) {
                int mid = (lo + hi) >> 1;
                if (batch[mid] < g) lo = mid + 1; else hi = mid;
            }
            return lo;
        };
        gcnt[tid] = lb(tid + 1) - lb(tid);
    }
}

__global__ void k_scan_c(const int* __restrict__ counts, const int* __restrict__ blockBase,
                         int* __restrict__ row_ptr) {
    __shared__ int sh[256];
    int tid = threadIdx.x;
    int gid = blockIdx.x * 256 + tid;
    int v = (gid < NN) ? counts[gid] : 0;
    sh[tid] = v;
    __syncthreads();
    for (int off = 1; off < 256; off <<= 1) {
        int t = (tid >= off) ? sh[tid - off] : 0;
        __syncthreads();
        sh[tid] += t;
        __syncthreads();
    }
    int excl = blockBase[blockIdx.x] + sh[tid] - v;
    if (gid <= NN) row_ptr[gid] = excl;
}

__global__ void k_place(const int* __restrict__ src, const int* __restrict__ dst,
                        const int* __restrict__ rank, const int* __restrict__ row_ptr,
                        int* __restrict__ csr_src) {
    int i = blockIdx.x * 256 + threadIdx.x;
    if (i < NE / 4) {
        int4 s4 = ((const int4*)src)[i];
        int4 d4 = ((const int4*)dst)[i];
        int4 r4 = ((const int4*)rank)[i];
        csr_src[row_ptr[d4.x] + r4.x] = s4.x;
        csr_src[row_ptr[d4.y] + r4.y] = s4.y;
        csr_src[row_ptr[d4.z] + r4.z] = s4.z;
        csr_src[row_ptr[d4.w] + r4.w] = s4.w;
    }
}

// ---------------- degree-sort permutation (two-level counting sort, no hotspots) ------
// Poisson(32) degrees -> per-block gather time = MAX over 32 nodes ~ 1.4x mean.
// perm groups equal-degree nodes into blocks -> max ~= mean. Bins = min(deg,255).
__global__ void k_dhist(const int* __restrict__ row_ptr, int* __restrict__ BH) {
    __shared__ int h[256];
    int tid = threadIdx.x;
    h[tid] = 0;
    __syncthreads();
    int gid = blockIdx.x * 256 + tid;
    if (gid < NN) {
        int d = row_ptr[gid + 1] - row_ptr[gid];
        if (d > 255) d = 255;
        atomicAdd(&h[d], 1);
    }
    __syncthreads();
    BH[blockIdx.x * 256 + tid] = h[tid];
}

__global__ void k_dscan(int* __restrict__ BH) {
    __shared__ int sh[256];
    int b = threadIdx.x;
    int run = 0;
    for (int blk = 0; blk < 196; ++blk) {
        int t = BH[blk * 256 + b];
        BH[blk * 256 + b] = run;      // exclusive along blocks, per bin
        run += t;
    }
    sh[b] = run;                       // bin totals
    __syncthreads();
    for (int off = 1; off < 256; off <<= 1) {
        int t = (b >= off) ? sh[b - off] : 0;
        __syncthreads();
        sh[b] += t;
        __syncthreads();
    }
    int base = sh[b] - run;            // exclusive bin base
    for (int blk = 0; blk < 196; ++blk)
        BH[blk * 256 + b] += base;     // now global start per (block,bin)
}

__global__ void k_dplace(const int* __restrict__ row_ptr, const int* __restrict__ BH,
                         int* __restrict__ perm) {
    __shared__ int h[256];
    int tid = threadIdx.x;
    h[tid] = 0;
    __syncthreads();
    int gid = blockIdx.x * 256 + tid;
    if (gid < NN) {
        int d = row_ptr[gid + 1] - row_ptr[gid];
        if (d > 255) d = 255;
        int lr = atomicAdd(&h[d], 1);
        perm[BH[blockIdx.x * 256 + d] + lr] = gid;
    }
}

// ======================================================================
// Fused layer, Ntile = 32 nodes/block, 256 threads (R10 structure + perm).
// Nodes are processed in DEGREE-SORTED order (perm): removes the Poisson
// max/mean ~1.4x gather tail per block. All node-indexed accesses go
// through pnod[]; outputs use absolute node ids so layer chaining and BN
// sums (order-free) are unaffected. Pooling moved OUT to k_pool3 (needs
// sorted batch; perm breaks block-local batch runs).
// Lin1/Lin2 + mlp GEMM on MFMA (bf16 hi/lo ~ 2^-17 rel). No VGPR spill:
// g=1 lo A-frags read on demand from live Agl (R10).
// LDS (27136 B): Agh[32][200] | Agl[32][200] | aux[352] | pnod[32]
//   (hsf 64x34 f32 overlays Agh after frag loads).
// ======================================================================
#define MBIAS(i) aux[i]
#define B1V(i)   aux[64 + (i)]
#define B2V(i)   aux[128 + (i)]
#define DEGV(m)  aux[192 + (m)]
#define AFFS(i)  aux[224 + (i)]
#define AFFB(i)  aux[288 + (i)]

__global__ __launch_bounds__(256, 4) void k_fused(
    const ushort* __restrict__ XHin, ushort* __restrict__ XHout,
    const int* __restrict__ perm,
    const int* __restrict__ row_ptr, const int* __restrict__ csr_src,
    const ushort* __restrict__ Wbh, const ushort* __restrict__ Wlin,
    const float* __restrict__ mlp_b,
    const float* __restrict__ b1, const float* __restrict__ b2,
    const float* __restrict__ affstat, const float* __restrict__ affg,
    const float* __restrict__ affb,
    float* __restrict__ bnstat) {
    __shared__ __align__(16) char smem[27136];
    ushort* const Agh = (ushort*)smem;                // 32 x 200 bf16 = 12800 B
    ushort* const Agl = (ushort*)(smem + 12800);      // 32 x 200 bf16 = 12800 B
    float* const aux = (float*)(smem + 25600);        // 352 f32
    int* const pnod = (int*)(smem + 27008);           // 32 ints
    float* const hsf = (float*)smem;                  // overlays Agh (64x34 f32 = 8704 B)

    const int tid = threadIdx.x;
    const int node0 = blockIdx.x * 32;

    if (tid < 64) {
        MBIAS(tid) = mlp_b[tid];
        B1V(tid) = b1[tid];
        B2V(tid) = b2[tid];
        float A = 1.f, Bv = 0.f;
        if (affstat) {
            float mean = affstat[tid] * (1.f / NN);
            float var = fmaxf(affstat[64 + tid] * (1.f / NN) - mean * mean, 0.f);
            float inv = rsqrtf(var + BN_EPS_F);
            A = affg[tid] * inv;           // > 0 (bn gamma = 1)
            Bv = affb[tid] - mean * A;
        }
        AFFS(tid) = A;
        AFFB(tid) = Bv;
    }
    if (tid < 32) {
        int sl = node0 + tid;
        pnod[tid] = (sl < NN) ? perm[sl] : -1;
    }
    __syncthreads();   // AFFS/AFFB/pnod visible

    // ---- gather: 32 groups of 8 lanes; 4-row double-buffered batches ----
    {
        const int l8 = tid & 7;
        const int m = tid >> 3;                // 0..31
        const int node = pnod[m];
        const int f0 = l8 * 8;
        const ushort* Xp = XHin + f0;

        float s[8], q[8], mx[8];
#pragma unroll
        for (int i = 0; i < 8; ++i) { s[i] = 0.f; q[i] = 0.f; mx[i] = -3.402823466e38f; }

        auto acc8 = [&](const uint4& rr) {
            float v0 = blo(rr.x), v1 = bhi(rr.x);
            float v2 = blo(rr.y), v3 = bhi(rr.y);
            float v4 = blo(rr.z), v5 = bhi(rr.z);
            float v6 = blo(rr.w), v7 = bhi(rr.w);
            s[0] += v0; q[0] = fmaf(v0, v0, q[0]); mx[0] = fmaxf(mx[0], v0);
            s[1] += v1; q[1] = fmaf(v1, v1, q[1]); mx[1] = fmaxf(mx[1], v1);
            s[2] += v2; q[2] = fmaf(v2, v2, q[2]); mx[2] = fmaxf(mx[2], v2);
            s[3] += v3; q[3] = fmaf(v3, v3, q[3]); mx[3] = fmaxf(mx[3], v3);
            s[4] += v4; q[4] = fmaf(v4, v4, q[4]); mx[4] = fmaxf(mx[4], v4);
            s[5] += v5; q[5] = fmaf(v5, v5, q[5]); mx[5] = fmaxf(mx[5], v5);
            s[6] += v6; q[6] = fmaf(v6, v6, q[6]); mx[6] = fmaxf(mx[6], v6);
            s[7] += v7; q[7] = fmaf(v7, v7, q[7]); mx[7] = fmaxf(mx[7], v7);
        };

        int beg = 0, end = 0;
        if (node >= 0) { beg = row_ptr[node]; end = row_ptr[node + 1]; }
        const int deg = end - beg;
        const int nb = (deg + 3) >> 2;

        uint4 ra[4], rb[4];
        int ia[4];
        if (nb > 0) {
#pragma unroll
            for (int j = 0; j < 4; ++j) {
                int e = beg + j;
                ia[j] = csr_src[(e < end) ? e : end - 1];
            }
#pragma unroll
            for (int j = 0; j < 4; ++j)
                ra[j] = *(const uint4*)(Xp + (size_t)ia[j] * 64);
            if (nb > 1) {
#pragma unroll
                for (int j = 0; j < 4; ++j) {
                    int e = beg + 4 + j;
                    ia[j] = csr_src[(e < end) ? e : end - 1];
                }
            }
        }
        for (int t = 0; t < nb; ++t) {
            if (t + 1 < nb) {
#pragma unroll
                for (int j = 0; j < 4; ++j)
                    rb[j] = *(const uint4*)(Xp + (size_t)ia[j] * 64);
            }
            if (t + 2 < nb) {
                int b2e = beg + (t + 2) * 4;
#pragma unroll
                for (int j = 0; j < 4; ++j) {
                    int e = b2e + j;
                    ia[j] = csr_src[(e < end) ? e : end - 1];
                }
            }
            int cnt = end - (beg + t * 4);
            if (cnt >= 4) {
#pragma unroll
                for (int j = 0; j < 4; ++j) acc8(ra[j]);
            } else {
#pragma unroll
                for (int j = 0; j < 4; ++j) if (j < cnt) acc8(ra[j]);
            }
            if (t + 1 < nb) {
#pragma unroll
                for (int j = 0; j < 4; ++j) ra[j] = rb[j];
            }
        }

        float cdeg = (node >= 0) ? (float)deg : 1.f;
        float rc = 1.0f / cdeg;
        float var[8];
#pragma unroll
        for (int i = 0; i < 8; ++i) {
            float mean = s[i] * rc;
            var[i] = fmaxf(q[i] * rc - mean * mean, 0.f);
            if (node < 0) { mx[i] = 0.f; var[i] = 0.f; }
        }
        // BN fold: stats of m = A*yraw + B from raw stats
#pragma unroll
        for (int i = 0; i < 8; ++i) {
            float Af = AFFS(f0 + i), Bf = AFFB(f0 + i);
            s[i] = Af * s[i] + cdeg * Bf;
            mx[i] = Af * mx[i] + Bf;
            var[i] = Af * Af * var[i];
        }
        // hi/lo bf16 stats -> Agh/Agl, [m][k] pitch 200
        ushort* dh = Agh + m * 200 + f0;
        ushort* dl = Agl + m * 200 + f0;
        auto emit8 = [&](const float* v, int off) {
            ushort h0 = f2bu(v[0]), h1 = f2bu(v[1]), h2 = f2bu(v[2]), h3 = f2bu(v[3]);
            ushort h4 = f2bu(v[4]), h5 = f2bu(v[5]), h6 = f2bu(v[6]), h7 = f2bu(v[7]);
            uint4 hv;
            hv.x = (unsigned)h0 | ((unsigned)h1 << 16);
            hv.y = (unsigned)h2 | ((unsigned)h3 << 16);
            hv.z = (unsigned)h4 | ((unsigned)h5 << 16);
            hv.w = (unsigned)h6 | ((unsigned)h7 << 16);
            uint4 lv;
            lv.x = pk(v[0] - bu2f(h0), v[1] - bu2f(h1));
            lv.y = pk(v[2] - bu2f(h2), v[3] - bu2f(h3));
            lv.z = pk(v[4] - bu2f(h4), v[5] - bu2f(h5));
            lv.w = pk(v[6] - bu2f(h6), v[7] - bu2f(h7));
            *(uint4*)(dh + off) = hv;
            *(uint4*)(dl + off) = lv;
        };
        emit8(s, 0);
        emit8(mx, 64);
        emit8(var, 128);
        if (l8 == 0) DEGV(m) = cdeg;
    }
    __syncthreads();

    // ---- load MFMA A hi fragments only (lo read on demand from live Agl) ----
    const int ln = tid & 63, wvi = tid >> 6;
    const int quad = ln >> 4, l16 = ln & 15;
    const int mtile = wvi >> 1;          // 0..1
    const int nt0 = (wvi & 1) * 2;       // ntiles nt0, nt0+1

    const ushort* ArowH = Agh + (mtile * 16 + l16) * 200 + quad * 8;
    const ushort* ArowL = Agl + (mtile * 16 + l16) * 200 + quad * 8;
    short8 afh[6];
#pragma unroll
    for (int i = 0; i < 6; ++i) {
        const int off = (i >> 1) * 64 + (i & 1) * 32;   // 0,32,64,96,128,160
        afh[i] = *(const short8*)(ArowH + off);
    }
    __syncthreads();   // Agh frag reads done -> hsf (Agh overlay) writable.
                       // Agl (bytes 12800+) is NOT overlaid -> lo frags read in-loop.

    // ---- MFMA: all three g-chunks; g=1 in hi/lo (3 MFMA per amplified kb) ----
#pragma unroll
    for (int nti = 0; nti < 2; ++nti) {
        const int nt = nt0 + nti;
        floatx4 aA0 = (floatx4){0.f, 0.f, 0.f, 0.f};
        floatx4 aB0 = (floatx4){0.f, 0.f, 0.f, 0.f};
        floatx4 aA1 = (floatx4){0.f, 0.f, 0.f, 0.f};
        floatx4 aB1 = (floatx4){0.f, 0.f, 0.f, 0.f};
        floatx4 aA2 = (floatx4){0.f, 0.f, 0.f, 0.f};
        floatx4 aB2 = (floatx4){0.f, 0.f, 0.f, 0.f};
#pragma unroll
        for (int kb = 0; kb < 8; ++kb) {
            const int am = (kb < 4) ? kb : ((kb < 6) ? (kb - 4) : (kb - 2));
            const int base = ((kb * 4 + nt) * 512) + ln * 8;
            short8 w0 = *(const short8*)(Wbh + base);                 // g=0
            short8 w1h = *(const short8*)(Wbh + 16384 + base);        // g=1 hi
            short8 w2 = *(const short8*)(Wbh + 3 * 16384 + base);     // g=2
            if (kb == 4 || kb == 5) {
                aB0 = __builtin_amdgcn_mfma_f32_16x16x32_bf16(afh[am], w0, aB0, 0, 0, 0);
                aB1 = __builtin_amdgcn_mfma_f32_16x16x32_bf16(afh[am], w1h, aB1, 0, 0, 0);
                aB2 = __builtin_amdgcn_mfma_f32_16x16x32_bf16(afh[am], w2, aB2, 0, 0, 0);
            } else {
                short8 w1l = *(const short8*)(Wbh + 2 * 16384 + base);  // g=1 lo
                short8 al = *(const short8*)(ArowL + ((am >> 1) * 64 + (am & 1) * 32));
                aA0 = __builtin_amdgcn_mfma_f32_16x16x32_bf16(afh[am], w0, aA0, 0, 0, 0);
                aA1 = __builtin_amdgcn_mfma_f32_16x16x32_bf16(afh[am], w1h, aA1, 0, 0, 0);
                aA1 = __builtin_amdgcn_mfma_f32_16x16x32_bf16(al, w1h, aA1, 0, 0, 0);
                aA1 = __builtin_amdgcn_mfma_f32_16x16x32_bf16(afh[am], w1l, aA1, 0, 0, 0);
                aA2 = __builtin_amdgcn_mfma_f32_16x16x32_bf16(afh[am], w2, aA2, 0, 0, 0);
            }
        }
        // partial -> hsf[n][m]
#pragma unroll
        for (int r = 0; r < 4; ++r) {
            int m = mtile * 16 + quad * 4 + r;
            float dg = DEGV(m), rcd = 1.f / dg;
            float cA2 = DELTA_F * rcd;
            float cB2 = DELTA_F * rcd * rcd;
            float cA1 = dg * (1.0f / DELTA_F);
            int n = nt * 16 + l16;
            hsf[n * 34 + m] = aA0[r] + rcd * aB0[r]
                            + cA2 * aA2[r] + cB2 * aB2[r]
                            + cA1 * aA1[r] + (1.0f / DELTA_F) * aB1[r];
        }
    }
    __syncthreads();   // all MFMA partials in hsf

    // ---- combine: h += x + bias, x = A*yraw_prev + B (BN'd residual) ----
    const int tx = tid & 15, ty = tid >> 4;
    const int o0 = tx * 4, n0 = ty * 2;
#pragma unroll
    for (int ni = 0; ni < 2; ++ni) {
        int n = n0 + ni;
        int node = pnod[n];
        float xa4[4] = {0.f, 0.f, 0.f, 0.f};
        if (node >= 0) {
            ushort4 hx = *(const ushort4*)(XHin + (size_t)node * DD + o0);
            xa4[0] = AFFS(o0 + 0) * bu2f(hx.x) + AFFB(o0 + 0);
            xa4[1] = AFFS(o0 + 1) * bu2f(hx.y) + AFFB(o0 + 1);
            xa4[2] = AFFS(o0 + 2) * bu2f(hx.z) + AFFB(o0 + 2);
            xa4[3] = AFFS(o0 + 3) * bu2f(hx.w) + AFFB(o0 + 3);
        }
#pragma unroll
        for (int oi = 0; oi < 4; ++oi) {
            int idx = (o0 + oi) * 34 + n;
            hsf[idx] = hsf[idx] + xa4[oi] + MBIAS(o0 + oi);
        }
    }
    __syncthreads();

    // ---- Lin1 (MFMA, hi/lo): A = h from hsf, W = Wlin frags; relu ----
    {
        floatx4 lacc[2];
        lacc[0] = (floatx4){0.f, 0.f, 0.f, 0.f};
        lacc[1] = (floatx4){0.f, 0.f, 0.f, 0.f};
#pragma unroll
        for (int kb = 0; kb < 2; ++kb) {
            short8 ah, al;
#pragma unroll
            for (int j = 0; j < 8; ++j) {
                float v = hsf[(kb * 32 + quad * 8 + j) * 34 + mtile * 16 + l16];
                ushort h = f2bu(v);
                ah[j] = (short)h;
                al[j] = (short)f2bu(v - bu2f(h));
            }
#pragma unroll
            for (int nti = 0; nti < 2; ++nti) {
                const int boff = ((kb * 4 + nt0 + nti) * 512) + ln * 8;
                short8 wh = *(const short8*)(Wlin + boff);
                short8 wl = *(const short8*)(Wlin + 4096 + boff);
                lacc[nti] = __builtin_amdgcn_mfma_f32_16x16x32_bf16(ah, wh, lacc[nti], 0, 0, 0);
                lacc[nti] = __builtin_amdgcn_mfma_f32_16x16x32_bf16(al, wh, lacc[nti], 0, 0, 0);
                lacc[nti] = __builtin_amdgcn_mfma_f32_16x16x32_bf16(ah, wl, lacc[nti], 0, 0, 0);
            }
        }
        __syncthreads();   // all A-reads done before overwriting hsf
#pragma unroll
        for (int nti = 0; nti < 2; ++nti) {
            int o = (nt0 + nti) * 16 + l16;
#pragma unroll
            for (int r = 0; r < 4; ++r)
                hsf[o * 34 + mtile * 16 + quad * 4 + r] = fmaxf(lacc[nti][r] + B1V(o), 0.f);
        }
    }
    __syncthreads();

    // ---- Lin2 (MFMA, hi/lo) + outer relu ----
    {
        floatx4 lacc[2];
        lacc[0] = (floatx4){0.f, 0.f, 0.f, 0.f};
        lacc[1] = (floatx4){0.f, 0.f, 0.f, 0.f};
#pragma unroll
        for (int kb = 0; kb < 2; ++kb) {
            short8 ah, al;
#pragma unroll
            for (int j = 0; j < 8; ++j) {
                float v = hsf[(kb * 32 + quad * 8 + j) * 34 + mtile * 16 + l16];
                ushort h = f2bu(v);
                ah[j] = (short)h;
                al[j] = (short)f2bu(v - bu2f(h));
            }
#pragma unroll
            for (int nti = 0; nti < 2; ++nti) {
                const int boff = ((kb * 4 + nt0 + nti) * 512) + ln * 8;
                short8 wh = *(const short8*)(Wlin + 8192 + boff);
                short8 wl = *(const short8*)(Wlin + 12288 + boff);
                lacc[nti] = __builtin_amdgcn_mfma_f32_16x16x32_bf16(ah, wh, lacc[nti], 0, 0, 0);
                lacc[nti] = __builtin_amdgcn_mfma_f32_16x16x32_bf16(al, wh, lacc[nti], 0, 0, 0);
                lacc[nti] = __builtin_amdgcn_mfma_f32_16x16x32_bf16(ah, wl, lacc[nti], 0, 0, 0);
            }
        }
        __syncthreads();
#pragma unroll
        for (int nti = 0; nti < 2; ++nti) {
            int o = (nt0 + nti) * 16 + l16;
#pragma unroll
            for (int r = 0; r < 4; ++r)
                hsf[o * 34 + mtile * 16 + quad * 4 + r] = fmaxf(lacc[nti][r] + B2V(o), 0.f);
        }
    }
    __syncthreads();

    // ---- write XHout (bf16) from hsf ----
    if (XHout) {
#pragma unroll
        for (int ni = 0; ni < 2; ++ni) {
            int n = n0 + ni;
            int node = pnod[n];
            if (node >= 0) {
                ushort4 h;
                h.x = f2bu(hsf[(o0 + 0) * 34 + n]);
                h.y = f2bu(hsf[(o0 + 1) * 34 + n]);
                h.z = f2bu(hsf[(o0 + 2) * 34 + n]);
                h.w = f2bu(hsf[(o0 + 3) * 34 + n]);
                *(ushort4*)(XHout + (size_t)node * DD + o0) = h;
            }
        }
    }

    // ---- BN partial sums (raw pre-BN y; order-free over valid columns) ----
    if (tid < 64) {
        float s = 0.f, sq = 0.f;
        int lim = NN - node0;
        if (lim > 32) lim = 32;
        for (int n = 0; n < lim; ++n) {
            float v = hsf[tid * 34 + n];
            s += v;
            sq += v * v;
        }
        atomicAdd(&bnstat[tid], s);
        atomicAdd(&bnstat[64 + tid], sq);
    }
}

// ---------------- pool: raw-sum layer-3 bf16 y into gpool (sorted batch) -------------
__global__ __launch_bounds__(256) void k_pool3(
    const ushort* __restrict__ YH, const int* __restrict__ batch,
    float* __restrict__ gpool) {
    __shared__ float pool[512];
    int tid = threadIdx.x;
    int i = blockIdx.x * 256 + tid;  // 8B-chunk index (4 feats)
    int n = i >> 4, fq = (i & 15) * 4;
    float4 r = make_float4(0.f, 0.f, 0.f, 0.f);
    bool valid = i < NN * 16;
    if (valid) {
        ushort4 h = *(const ushort4*)(YH + (size_t)n * DD + fq);
        r.x = bu2f(h.x); r.y = bu2f(h.y); r.z = bu2f(h.z); r.w = bu2f(h.w);
    }
    int nfirst = blockIdx.x * 16;
    int nlast = nfirst + 15;
    if (nlast >= NN) nlast = NN - 1;
    int gmin = batch[nfirst], gmax = batch[nlast];
    int span = gmax - gmin + 1;
    if (span <= 8) {
        for (int j = tid; j < span * 64; j += 256) pool[j] = 0.f;
        __syncthreads();
        if (valid) {
            int gb = batch[n] - gmin;
            atomicAdd(&pool[gb * 64 + fq + 0], r.x);
            atomicAdd(&pool[gb * 64 + fq + 1], r.y);
            atomicAdd(&pool[gb * 64 + fq + 2], r.z);
            atomicAdd(&pool[gb * 64 + fq + 3], r.w);
        }
        __syncthreads();
        for (int j = tid; j < span * 64; j += 256)
            atomicAdd(&gpool[(size_t)(gmin + (j >> 6)) * 64 + (j & 63)], pool[j]);
    } else {
        if (valid) {
            float* gp = gpool + (size_t)batch[n] * DD + fq;
            atomicAdd(gp + 0, r.x);
            atomicAdd(gp + 1, r.y);
            atomicAdd(gp + 2, r.z);
            atomicAdd(gp + 3, r.w);
        }
    }
}

// ---------------- head: BN3-affine on raw pool, fc1+relu, fc2, log_softmax ----------
__global__ __launch_bounds__(256) void k_head(const float* __restrict__ gpool,
                                              const float* __restrict__ bs3,
                                              const float* __restrict__ g3,
                                              const float* __restrict__ b3,
                                              const int* __restrict__ gcnt,
                                              const float* __restrict__ fc1W, const float* __restrict__ fc1b,
                                              const float* __restrict__ fc2W, const float* __restrict__ fc2b,
                                              float* __restrict__ out) {
    __shared__ float sh[12640];
    float* const gs = sh;
    float* const w1t = sh + 4096;
    float* const z1s = sh + 8256;
    float* const b1s = sh + 12416;
    float* const b2s = sh + 12480;
    float* const sc3 = sh + 12512;
    float* const shf3 = sh + 12576;
    float* const w2t = sh;
    float* const z2s = sh + 4096;

    int tid = threadIdx.x;
    if (tid < 64) {
        float mean = bs3[tid] * (1.f / NN);
        float var = fmaxf(bs3[64 + tid] * (1.f / NN) - mean * mean, 0.f);
        float inv = rsqrtf(var + BN_EPS_F);
        float A = g3[tid] * inv;
        sc3[tid] = A;
        shf3[tid] = b3[tid] - mean * A;
    }
    __syncthreads();
    for (int i = tid; i < 4096; i += 256) {
        int o = i >> 6, j = i & 63;
        gs[i] = sc3[j] * gpool[i] + shf3[j] * (float)gcnt[o];
        w1t[j * 65 + o] = fc1W[i];
    }
    if (tid < 64) b1s[tid] = fc1b[tid];
    if (tid < 32) b2s[tid] = fc2b[tid];
    __syncthreads();
    {
        int tx = tid & 15, ty = tid >> 4, o0 = tx * 4, g0 = ty * 4;
        float acc[16];
#pragma unroll
        for (int i = 0; i < 16; ++i) acc[i] = 0.f;
        for (int j = 0; j < 64; ++j) {
            float w0 = w1t[j * 65 + o0 + 0], w1 = w1t[j * 65 + o0 + 1];
            float w2 = w1t[j * 65 + o0 + 2], w3 = w1t[j * 65 + o0 + 3];
#pragma unroll
            for (int gi = 0; gi < 4; ++gi) {
                float a = gs[(g0 + gi) * 64 + j];
                acc[gi * 4 + 0] += a * w0; acc[gi * 4 + 1] += a * w1;
                acc[gi * 4 + 2] += a * w2; acc[gi * 4 + 3] += a * w3;
            }
        }
        __syncthreads();
#pragma unroll
        for (int gi = 0; gi < 4; ++gi)
#pragma unroll
            for (int oi = 0; oi < 4; ++oi)
                z1s[(g0 + gi) * 65 + o0 + oi] = fmaxf(acc[gi * 4 + oi] + b1s[o0 + oi], 0.f);
    }
    for (int i = tid; i < 2048; i += 256) {
        int o = i >> 6, j = i & 63;
        w2t[j * 33 + o] = fc2W[i];
    }
    __syncthreads();
    {
        int tx = tid & 7, ty = tid >> 3, o0 = tx * 4, g0 = ty * 2;
        float acc[8];
#pragma unroll
        for (int i = 0; i < 8; ++i) acc[i] = 0.f;
        for (int j = 0; j < 64; ++j) {
            float w0 = w2t[j * 33 + o0 + 0], w1 = w2t[j * 33 + o0 + 1];
            float w2 = w2t[j * 33 + o0 + 2], w3 = w2t[j * 33 + o0 + 3];
            float a0 = z1s[(g0 + 0) * 65 + j];
            float a1 = z1s[(g0 + 1) * 65 + j];
            acc[0] += a0 * w0; acc[1] += a0 * w1; acc[2] += a0 * w2; acc[3] += a0 * w3;
            acc[4] += a1 * w0; acc[5] += a1 * w1; acc[6] += a1 * w2; acc[7] += a1 * w3;
        }
#pragma unroll
        for (int gi = 0; gi < 2; ++gi)
#pragma unroll
            for (int oi = 0; oi < 4; ++oi)
                z2s[(g0 + gi) * 33 + o0 + oi] = acc[gi * 4 + oi] + b2s[o0 + oi];
    }
    __syncthreads();
    if (tid < 64) {
        float m = -3.402823466e38f;
        for (int c = 0; c < DOUT; ++c) m = fmaxf(m, z2s[tid * 33 + c]);
        float s = 0.f;
        for (int c = 0; c < DOUT; ++c) s += expf(z2s[tid * 33 + c] - m);
        float lse = m + logf(s);
        for (int c = 0; c < DOUT; ++c)
            out[tid * DOUT + c] = z2s[tid * 33 + c] - lse;
    }
}

extern "C" void kernel_launch(void* const* d_in, const int* in_sizes, int n_in,
                              void* d_out, int out_size, void* d_ws, size_t ws_size,
                              hipStream_t stream) {
    const float* x = (const float*)d_in[0];
    const int* ei = (const int*)d_in[1];
    const int* src = ei;
    const int* dst = ei + NE;
    const int* batch = (const int*)d_in[2];
    const float *mlpW[3], *mlpB[3], *w1[3], *bb1[3], *w2[3], *bb2[3], *bng[3], *bnb[3];
    for (int l = 0; l < 3; ++l) {
        mlpW[l] = (const float*)d_in[3 + 6 * l];
        mlpB[l] = (const float*)d_in[4 + 6 * l];
        w1[l]   = (const float*)d_in[5 + 6 * l];
        bb1[l]  = (const float*)d_in[6 + 6 * l];
        w2[l]   = (const float*)d_in[7 + 6 * l];
        bb2[l]  = (const float*)d_in[8 + 6 * l];
        bng[l]  = (const float*)d_in[21 + 2 * l];
        bnb[l]  = (const float*)d_in[22 + 2 * l];
    }
    const float* fc1W = (const float*)d_in[27];
    const float* fc1b = (const float*)d_in[28];
    const float* fc2W = (const float*)d_in[29];
    const float* fc2b = (const float*)d_in[30];
    float* out = (float*)d_out;

    char* ws = (char*)d_ws;
    size_t off = 0;
    auto alloc = [&](size_t bytes) -> void* {
        void* p = ws + off;
        off = (off + bytes + 511) & ~(size_t)511;
        return p;
    };
    int* counts    = (int*)alloc((size_t)NN * 4);
    int* row_ptr   = (int*)alloc((size_t)(NN + 1) * 4);
    int* rank      = (int*)alloc((size_t)NE * 4);
    int* blockSums = (int*)alloc(256 * 4);
    int* blockBase = (int*)alloc(256 * 4);
    int* csr_src   = (int*)alloc((size_t)NE * 4);
    int* blockHist = (int*)alloc((size_t)196 * 256 * 4);
    int* perm      = (int*)alloc((size_t)NN * 4);
    ushort* XHA    = (ushort*)alloc((size_t)NN * DD * 2);
    ushort* XHB    = (ushort*)alloc((size_t)NN * DD * 2);
    ushort* Wb     = (ushort*)alloc((size_t)3 * 65536 * 2);
    ushort* Wsb    = (ushort*)alloc((size_t)3 * 16384 * 2);
    float* bnstat  = (float*)alloc(384 * 4);
    float* gpool   = (float*)alloc((size_t)NGRAPH * DD * 4);
    int* gcnt      = (int*)alloc(NGRAPH * 4);
    (void)ws_size; (void)in_sizes; (void)n_in; (void)out_size;

    k_prep<<<3125, 256, 0, stream>>>(x, XHA,
                                     mlpW[0], mlpW[1], mlpW[2],
                                     w1[0], w2[0], w1[1], w2[1], w1[2], w2[2],
                                     Wb, Wsb, counts, bnstat, gpool);
    k_rank<<<1563, 256, 0, stream>>>(dst, counts, rank);
    k_scan_a<<<196, 256, 0, stream>>>(counts, blockSums);
    k_scan_b<<<1, 256, 0, stream>>>(blockSums, blockBase, batch, gcnt);
    k_scan_c<<<196, 256, 0, stream>>>(counts, blockBase, row_ptr);
    k_place<<<1563, 256, 0, stream>>>(src, dst, rank, row_ptr, csr_src);
    k_dhist<<<196, 256, 0, stream>>>(row_ptr, blockHist);
    k_dscan<<<1, 256, 0, stream>>>(blockHist);
    k_dplace<<<196, 256, 0, stream>>>(row_ptr, blockHist, perm);

    // layer 1: in XHA (identity affine), out XHB (raw bf16 y)
    k_fused<<<1563, 256, 0, stream>>>(XHA, XHB, perm, row_ptr, csr_src,
                                      Wb, Wsb, mlpB[0], bb1[0], bb2[0],
                                      nullptr, nullptr, nullptr,
                                      bnstat);
    // layer 2: in XHB (affine from bnstat[0]), out XHA
    k_fused<<<1563, 256, 0, stream>>>(XHB, XHA, perm, row_ptr, csr_src,
                                      Wb + 65536, Wsb + 16384, mlpB[1], bb1[1], bb2[1],
                                      bnstat, bng[0], bnb[0],
                                      bnstat + 128);
    // layer 3: in XHA (affine from bnstat[1]), out XHB (raw bf16 y)
    k_fused<<<1563, 256, 0, stream>>>(XHA, XHB, perm, row_ptr, csr_src,
                                      Wb + 2 * 65536, Wsb + 2 * 16384, mlpB[2], bb1[2], bb2[2],
                                      bnstat + 128, bng[1], bnb[1],
                                      bnstat + 256);
    k_pool3<<<3125, 256, 0, stream>>>(XHB, batch, gpool);
    k_head<<<1, 256, 0, stream>>>(gpool, bnstat + 256, bng[2], bnb[2], gcnt,
                                  fc1W, fc1b, fc2W, fc2b, out);
}

// Round 12
// 474.607 us; speedup vs baseline: 1.0288x; 1.0288x over previous
//
#include <hip/hip_runtime.h>

#define NN 50000
#define NE 1600000
#define DD 64
#define NGRAPH 64
#define DOUT 32
#define DELTA_F 2.5749f
#define BN_EPS_F 1e-5f

typedef unsigned short ushort;
typedef __attribute__((ext_vector_type(8))) short short8;
typedef __attribute__((ext_vector_type(4))) float floatx4;

static __device__ __forceinline__ float blo(unsigned u) {
    return __uint_as_float(u << 16);
}
static __device__ __forceinline__ float bhi(unsigned u) {
    return __uint_as_float(u & 0xFFFF0000u);
}
static __device__ __forceinline__ float bu2f(ushort u) {
    return __uint_as_float(((unsigned)u) << 16);
}
static __device__ __forceinline__ ushort f2bu(float f) {
    unsigned u = __float_as_uint(f);
    unsigned r = (u + 0x7FFF + ((u >> 16) & 1)) >> 16;   // round-to-nearest-even
    return (ushort)r;
}
static __device__ __forceinline__ unsigned pk(float a, float b) {
    return ((unsigned)f2bu(b) << 16) | (unsigned)f2bu(a);
}

// ---------------- prep: init + x->bf16 + weight prep (fused, 1 launch) ----------------
__global__ void k_prep(const float* __restrict__ x, ushort* __restrict__ XH,
                       const float* __restrict__ w0, const float* __restrict__ w1,
                       const float* __restrict__ w2,
                       const float* __restrict__ a0, const float* __restrict__ a1,
                       const float* __restrict__ a2, const float* __restrict__ a3,
                       const float* __restrict__ a4, const float* __restrict__ a5,
                       ushort* __restrict__ Wb, ushort* __restrict__ Wsb,
                       int* __restrict__ counts, float* __restrict__ bnstat,
                       float* __restrict__ gpool) {
    int i = blockIdx.x * 256 + threadIdx.x;
    if (i < NN) counts[i] = 0;
    if (i < 384) bnstat[i] = 0.f;
    if (i < NGRAPH * DD) gpool[i] = 0.f;
    if (i < NN * 16) {
        float4 v = *(const float4*)(x + (size_t)i * 4);
        ushort4 h;
        h.x = f2bu(v.x); h.y = f2bu(v.y); h.z = f2bu(v.z); h.w = f2bu(v.w);
        *(ushort4*)(XH + (size_t)i * 4) = h;
    }
    if (i < 3 * 65536) {
        int layer = i / 65536, r = i % 65536;
        const float* w = (layer == 0) ? w0 : ((layer == 1) ? w1 : w2);
        int c = r / 16384, r2 = r % 16384;
        int kb = r2 >> 11, r3 = r2 & 2047;
        int t = r3 >> 9, r4 = r3 & 511;
        int l = r4 >> 3, j = r4 & 7;
        int k = kb * 32 + (l >> 4) * 8 + j;
        int o = t * 16 + (l & 15);
        int g = (c == 0) ? 0 : ((c == 3) ? 2 : 1);
        float wv = w[o * 768 + g * 256 + k];
        ushort h = f2bu(wv);
        Wb[i] = (c == 2) ? f2bu(wv - bu2f(h)) : h;
    } else if (i < 3 * 65536 + 3 * 16384) {
        int i2 = i - 3 * 65536;
        int layer = i2 / 16384, r = i2 % 16384;
        int lin = r >> 13, r2 = r & 8191;
        int hl = r2 >> 12, r3 = r2 & 4095;
        int kb = r3 >> 11, r4 = r3 & 2047;
        int t = r4 >> 9, r5 = r4 & 511;
        int l = r5 >> 3, j = r5 & 7;
        int k = kb * 32 + (l >> 4) * 8 + j;
        int o = t * 16 + (l & 15);
        const float* w = (lin == 0)
            ? ((layer == 0) ? a0 : (layer == 1) ? a2 : a4)
            : ((layer == 0) ? a1 : (layer == 1) ? a3 : a5);
        float wv = w[o * 64 + k];
        ushort h = f2bu(wv);
        Wsb[i2] = hl ? f2bu(wv - bu2f(h)) : h;
    }
}

// ---------------- CSR build (rank/scan/place — single atomic pass, int4 loads) --------
__global__ void k_rank(const int* __restrict__ dst, int* __restrict__ counts,
                       int* __restrict__ rank) {
    int i = blockIdx.x * 256 + threadIdx.x;
    if (i < NE / 4) {
        int4 d = ((const int4*)dst)[i];
        int4 r;
        r.x = atomicAdd(&counts[d.x], 1);
        r.y = atomicAdd(&counts[d.y], 1);
        r.z = atomicAdd(&counts[d.z], 1);
        r.w = atomicAdd(&counts[d.w], 1);
        ((int4*)rank)[i] = r;
    }
}

// block-sum reduction + degree histogram (counts[gid] = degree after k_rank)
__global__ void k_scan_a(const int* __restrict__ counts, int* __restrict__ blockSums,
                         int* __restrict__ BH) {
    __shared__ int red[256];
    __shared__ int h[256];
    int tid = threadIdx.x;
    h[tid] = 0;
    int gid = blockIdx.x * 256 + tid;
    int v = (gid < NN) ? counts[gid] : 0;
    red[tid] = v;
    __syncthreads();
    if (gid < NN) {
        int d = (v > 255) ? 255 : v;
        atomicAdd(&h[d], 1);
    }
    for (int s = 128; s > 0; s >>= 1) {
        if (tid < s) red[tid] += red[tid + s];
        __syncthreads();
    }
    if (tid == 0) blockSums[blockIdx.x] = red[0];
    BH[blockIdx.x * 256 + tid] = h[tid];
}

// per-bin exclusive prefix over the 196 blocks (256 blocks, one bin each; parallel —
// R11's single-block serial version cost ~35us of dependent global latency)
__global__ void k_dscanA(int* __restrict__ BH, int* __restrict__ binTot) {
    __shared__ int sh[256];
    int b = blockIdx.x;
    int t = threadIdx.x;
    int v = (t < 196) ? BH[t * 256 + b] : 0;
    sh[t] = v;
    __syncthreads();
    for (int off = 1; off < 256; off <<= 1) {
        int tv = (t >= off) ? sh[t - off] : 0;
        __syncthreads();
        sh[t] += tv;
        __syncthreads();
    }
    if (t < 196) BH[t * 256 + b] = sh[t] - v;   // exclusive along blocks
    if (t == 255) binTot[b] = sh[255];
}

// blockBase scan + gcnt (binary search) + binBase scan (all 1 block)
__global__ void k_scan_b(const int* __restrict__ blockSums, int* __restrict__ blockBase,
                         const int* __restrict__ batch, int* __restrict__ gcnt,
                         const int* __restrict__ binTot, int* __restrict__ binBase) {
    __shared__ int sh[256];
    int tid = threadIdx.x;
    int v = (tid < 196) ? blockSums[tid] : 0;
    sh[tid] = v;
    __syncthreads();
    for (int off = 1; off < 256; off <<= 1) {
        int t = (tid >= off) ? sh[tid - off] : 0;
        __syncthreads();
        sh[tid] += t;
        __syncthreads();
    }
    blockBase[tid] = sh[tid] - v;  // exclusive
    if (tid < NGRAPH) {
        auto lb = [&](int g) {
            int lo = 0, hi = NN;
            while (lo < hi) {
                int mid = (lo + hi) >> 1;
                if (batch[mid] < g) lo = mid + 1; else hi = mid;
            }
            return lo;
        };
        gcnt[tid] = lb(tid + 1) - lb(tid);
    }
    __syncthreads();   // done reading sh from first scan
    int bv = binTot[tid];
    sh[tid] = bv;
    __syncthreads();
    for (int off = 1; off < 256; off <<= 1) {
        int t = (tid >= off) ? sh[tid - off] : 0;
        __syncthreads();
        sh[tid] += t;
        __syncthreads();
    }
    binBase[tid] = sh[tid] - bv;   // exclusive bin base
}

__global__ void k_scan_c(const int* __restrict__ counts, const int* __restrict__ blockBase,
                         int* __restrict__ row_ptr) {
    __shared__ int sh[256];
    int tid = threadIdx.x;
    int gid = blockIdx.x * 256 + tid;
    int v = (gid < NN) ? counts[gid] : 0;
    sh[tid] = v;
    __syncthreads();
    for (int off = 1; off < 256; off <<= 1) {
        int t = (tid >= off) ? sh[tid - off] : 0;
        __syncthreads();
        sh[tid] += t;
        __syncthreads();
    }
    int excl = blockBase[blockIdx.x] + sh[tid] - v;
    if (gid <= NN) row_ptr[gid] = excl;
}

__global__ void k_place(const int* __restrict__ src, const int* __restrict__ dst,
                        const int* __restrict__ rank, const int* __restrict__ row_ptr,
                        int* __restrict__ csr_src) {
    int i = blockIdx.x * 256 + threadIdx.x;
    if (i < NE / 4) {
        int4 s4 = ((const int4*)src)[i];
        int4 d4 = ((const int4*)dst)[i];
        int4 r4 = ((const int4*)rank)[i];
        csr_src[row_ptr[d4.x] + r4.x] = s4.x;
        csr_src[row_ptr[d4.y] + r4.y] = s4.y;
        csr_src[row_ptr[d4.z] + r4.z] = s4.z;
        csr_src[row_ptr[d4.w] + r4.w] = s4.w;
    }
}

// place nodes into degree-sorted perm (counts[] still holds degrees)
__global__ void k_dplace(const int* __restrict__ counts, const int* __restrict__ BH,
                         const int* __restrict__ binBase, int* __restrict__ perm) {
    __shared__ int h[256];
    __shared__ int bb[256];
    int tid = threadIdx.x;
    h[tid] = 0;
    bb[tid] = binBase[tid] + BH[blockIdx.x * 256 + tid];
    __syncthreads();
    int gid = blockIdx.x * 256 + tid;
    if (gid < NN) {
        int d = counts[gid];
        if (d > 255) d = 255;
        int lr = atomicAdd(&h[d], 1);
        perm[bb[d] + lr] = gid;
    }
}

// ======================================================================
// Fused layer (R11 verbatim): Ntile=32, 256 threads, degree-sorted perm,
// MFMA mlp GEMM (g=1 hi/lo) + MFMA Lin1/Lin2 (hi/lo), BN folded into
// gather stats, no VGPR spill. 71.7us/layer measured.
// ======================================================================
#define MBIAS(i) aux[i]
#define B1V(i)   aux[64 + (i)]
#define B2V(i)   aux[128 + (i)]
#define DEGV(m)  aux[192 + (m)]
#define AFFS(i)  aux[224 + (i)]
#define AFFB(i)  aux[288 + (i)]

__global__ __launch_bounds__(256, 4) void k_fused(
    const ushort* __restrict__ XHin, ushort* __restrict__ XHout,
    const int* __restrict__ perm,
    const int* __restrict__ row_ptr, const int* __restrict__ csr_src,
    const ushort* __restrict__ Wbh, const ushort* __restrict__ Wlin,
    const float* __restrict__ mlp_b,
    const float* __restrict__ b1, const float* __restrict__ b2,
    const float* __restrict__ affstat, const float* __restrict__ affg,
    const float* __restrict__ affb,
    float* __restrict__ bnstat) {
    __shared__ __align__(16) char smem[27136];
    ushort* const Agh = (ushort*)smem;                // 32 x 200 bf16 = 12800 B
    ushort* const Agl = (ushort*)(smem + 12800);      // 32 x 200 bf16 = 12800 B
    float* const aux = (float*)(smem + 25600);        // 352 f32
    int* const pnod = (int*)(smem + 27008);           // 32 ints
    float* const hsf = (float*)smem;                  // overlays Agh (64x34 f32 = 8704 B)

    const int tid = threadIdx.x;
    const int node0 = blockIdx.x * 32;

    if (tid < 64) {
        MBIAS(tid) = mlp_b[tid];
        B1V(tid) = b1[tid];
        B2V(tid) = b2[tid];
        float A = 1.f, Bv = 0.f;
        if (affstat) {
            float mean = affstat[tid] * (1.f / NN);
            float var = fmaxf(affstat[64 + tid] * (1.f / NN) - mean * mean, 0.f);
            float inv = rsqrtf(var + BN_EPS_F);
            A = affg[tid] * inv;           // > 0 (bn gamma = 1)
            Bv = affb[tid] - mean * A;
        }
        AFFS(tid) = A;
        AFFB(tid) = Bv;
    }
    if (tid < 32) {
        int sl = node0 + tid;
        pnod[tid] = (sl < NN) ? perm[sl] : -1;
    }
    __syncthreads();   // AFFS/AFFB/pnod visible

    // ---- gather: 32 groups of 8 lanes; 4-row double-buffered batches ----
    {
        const int l8 = tid & 7;
        const int m = tid >> 3;                // 0..31
        const int node = pnod[m];
        const int f0 = l8 * 8;
        const ushort* Xp = XHin + f0;

        float s[8], q[8], mx[8];
#pragma unroll
        for (int i = 0; i < 8; ++i) { s[i] = 0.f; q[i] = 0.f; mx[i] = -3.402823466e38f; }

        auto acc8 = [&](const uint4& rr) {
            float v0 = blo(rr.x), v1 = bhi(rr.x);
            float v2 = blo(rr.y), v3 = bhi(rr.y);
            float v4 = blo(rr.z), v5 = bhi(rr.z);
            float v6 = blo(rr.w), v7 = bhi(rr.w);
            s[0] += v0; q[0] = fmaf(v0, v0, q[0]); mx[0] = fmaxf(mx[0], v0);
            s[1] += v1; q[1] = fmaf(v1, v1, q[1]); mx[1] = fmaxf(mx[1], v1);
            s[2] += v2; q[2] = fmaf(v2, v2, q[2]); mx[2] = fmaxf(mx[2], v2);
            s[3] += v3; q[3] = fmaf(v3, v3, q[3]); mx[3] = fmaxf(mx[3], v3);
            s[4] += v4; q[4] = fmaf(v4, v4, q[4]); mx[4] = fmaxf(mx[4], v4);
            s[5] += v5; q[5] = fmaf(v5, v5, q[5]); mx[5] = fmaxf(mx[5], v5);
            s[6] += v6; q[6] = fmaf(v6, v6, q[6]); mx[6] = fmaxf(mx[6], v6);
            s[7] += v7; q[7] = fmaf(v7, v7, q[7]); mx[7] = fmaxf(mx[7], v7);
        };

        int beg = 0, end = 0;
        if (node >= 0) { beg = row_ptr[node]; end = row_ptr[node + 1]; }
        const int deg = end - beg;
        const int nb = (deg + 3) >> 2;

        uint4 ra[4], rb[4];
        int ia[4];
        if (nb > 0) {
#pragma unroll
            for (int j = 0; j < 4; ++j) {
                int e = beg + j;
                ia[j] = csr_src[(e < end) ? e : end - 1];
            }
#pragma unroll
            for (int j = 0; j < 4; ++j)
                ra[j] = *(const uint4*)(Xp + (size_t)ia[j] * 64);
            if (nb > 1) {
#pragma unroll
                for (int j = 0; j < 4; ++j) {
                    int e = beg + 4 + j;
                    ia[j] = csr_src[(e < end) ? e : end - 1];
                }
            }
        }
        for (int t = 0; t < nb; ++t) {
            if (t + 1 < nb) {
#pragma unroll
                for (int j = 0; j < 4; ++j)
                    rb[j] = *(const uint4*)(Xp + (size_t)ia[j] * 64);
            }
            if (t + 2 < nb) {
                int b2e = beg + (t + 2) * 4;
#pragma unroll
                for (int j = 0; j < 4; ++j) {
                    int e = b2e + j;
                    ia[j] = csr_src[(e < end) ? e : end - 1];
                }
            }
            int cnt = end - (beg + t * 4);
            if (cnt >= 4) {
#pragma unroll
                for (int j = 0; j < 4; ++j) acc8(ra[j]);
            } else {
#pragma unroll
                for (int j = 0; j < 4; ++j) if (j < cnt) acc8(ra[j]);
            }
            if (t + 1 < nb) {
#pragma unroll
                for (int j = 0; j < 4; ++j) ra[j] = rb[j];
            }
        }

        float cdeg = (node >= 0) ? (float)deg : 1.f;
        float rc = 1.0f / cdeg;
        float var[8];
#pragma unroll
        for (int i = 0; i < 8; ++i) {
            float mean = s[i] * rc;
            var[i] = fmaxf(q[i] * rc - mean * mean, 0.f);
            if (node < 0) { mx[i] = 0.f; var[i] = 0.f; }
        }
        // BN fold: stats of m = A*yraw + B from raw stats
#pragma unroll
        for (int i = 0; i < 8; ++i) {
            float Af = AFFS(f0 + i), Bf = AFFB(f0 + i);
            s[i] = Af * s[i] + cdeg * Bf;
            mx[i] = Af * mx[i] + Bf;
            var[i] = Af * Af * var[i];
        }
        // hi/lo bf16 stats -> Agh/Agl, [m][k] pitch 200
        ushort* dh = Agh + m * 200 + f0;
        ushort* dl = Agl + m * 200 + f0;
        auto emit8 = [&](const float* v, int off) {
            ushort h0 = f2bu(v[0]), h1 = f2bu(v[1]), h2 = f2bu(v[2]), h3 = f2bu(v[3]);
            ushort h4 = f2bu(v[4]), h5 = f2bu(v[5]), h6 = f2bu(v[6]), h7 = f2bu(v[7]);
            uint4 hv;
            hv.x = (unsigned)h0 | ((unsigned)h1 << 16);
            hv.y = (unsigned)h2 | ((unsigned)h3 << 16);
            hv.z = (unsigned)h4 | ((unsigned)h5 << 16);
            hv.w = (unsigned)h6 | ((unsigned)h7 << 16);
            uint4 lv;
            lv.x = pk(v[0] - bu2f(h0), v[1] - bu2f(h1));
            lv.y = pk(v[2] - bu2f(h2), v[3] - bu2f(h3));
            lv.z = pk(v[4] - bu2f(h4), v[5] - bu2f(h5));
            lv.w = pk(v[6] - bu2f(h6), v[7] - bu2f(h7));
            *(uint4*)(dh + off) = hv;
            *(uint4*)(dl + off) = lv;
        };
        emit8(s, 0);
        emit8(mx, 64);
        emit8(var, 128);
        if (l8 == 0) DEGV(m) = cdeg;
    }
    __syncthreads();

    // ---- load MFMA A hi fragments only (lo read on demand from live Agl) ----
    const int ln = tid & 63, wvi = tid >> 6;
    const int quad = ln >> 4, l16 = ln & 15;
    const int mtile = wvi >> 1;          // 0..1
    const int nt0 = (wvi & 1) * 2;       // ntiles nt0, nt0+1

    const ushort* ArowH = Agh + (mtile * 16 + l16) * 200 + quad * 8;
    const ushort* ArowL = Agl + (mtile * 16 + l16) * 200 + quad * 8;
    short8 afh[6];
#pragma unroll
    for (int i = 0; i < 6; ++i) {
        const int off = (i >> 1) * 64 + (i & 1) * 32;   // 0,32,64,96,128,160
        afh[i] = *(const short8*)(ArowH + off);
    }
    __syncthreads();   // Agh frag reads done -> hsf (Agh overlay) writable.
                       // Agl (bytes 12800+) is NOT overlaid -> lo frags read in-loop.

    // ---- MFMA: all three g-chunks; g=1 in hi/lo (3 MFMA per amplified kb) ----
#pragma unroll
    for (int nti = 0; nti < 2; ++nti) {
        const int nt = nt0 + nti;
        floatx4 aA0 = (floatx4){0.f, 0.f, 0.f, 0.f};
        floatx4 aB0 = (floatx4){0.f, 0.f, 0.f, 0.f};
        floatx4 aA1 = (floatx4){0.f, 0.f, 0.f, 0.f};
        floatx4 aB1 = (floatx4){0.f, 0.f, 0.f, 0.f};
        floatx4 aA2 = (floatx4){0.f, 0.f, 0.f, 0.f};
        floatx4 aB2 = (floatx4){0.f, 0.f, 0.f, 0.f};
#pragma unroll
        for (int kb = 0; kb < 8; ++kb) {
            const int am = (kb < 4) ? kb : ((kb < 6) ? (kb - 4) : (kb - 2));
            const int base = ((kb * 4 + nt) * 512) + ln * 8;
            short8 w0 = *(const short8*)(Wbh + base);                 // g=0
            short8 w1h = *(const short8*)(Wbh + 16384 + base);        // g=1 hi
            short8 w2 = *(const short8*)(Wbh + 3 * 16384 + base);     // g=2
            if (kb == 4 || kb == 5) {
                aB0 = __builtin_amdgcn_mfma_f32_16x16x32_bf16(afh[am], w0, aB0, 0, 0, 0);
                aB1 = __builtin_amdgcn_mfma_f32_16x16x32_bf16(afh[am], w1h, aB1, 0, 0, 0);
                aB2 = __builtin_amdgcn_mfma_f32_16x16x32_bf16(afh[am], w2, aB2, 0, 0, 0);
            } else {
                short8 w1l = *(const short8*)(Wbh + 2 * 16384 + base);  // g=1 lo
                short8 al = *(const short8*)(ArowL + ((am >> 1) * 64 + (am & 1) * 32));
                aA0 = __builtin_amdgcn_mfma_f32_16x16x32_bf16(afh[am], w0, aA0, 0, 0, 0);
                aA1 = __builtin_amdgcn_mfma_f32_16x16x32_bf16(afh[am], w1h, aA1, 0, 0, 0);
                aA1 = __builtin_amdgcn_mfma_f32_16x16x32_bf16(al, w1h, aA1, 0, 0, 0);
                aA1 = __builtin_amdgcn_mfma_f32_16x16x32_bf16(afh[am], w1l, aA1, 0, 0, 0);
                aA2 = __builtin_amdgcn_mfma_f32_16x16x32_bf16(afh[am], w2, aA2, 0, 0, 0);
            }
        }
        // partial -> hsf[n][m]
#pragma unroll
        for (int r = 0; r < 4; ++r) {
            int m = mtile * 16 + quad * 4 + r;
            float dg = DEGV(m), rcd = 1.f / dg;
            float cA2 = DELTA_F * rcd;
            float cB2 = DELTA_F * rcd * rcd;
            float cA1 = dg * (1.0f / DELTA_F);
            int n = nt * 16 + l16;
            hsf[n * 34 + m] = aA0[r] + rcd * aB0[r]
                            + cA2 * aA2[r] + cB2 * aB2[r]
                            + cA1 * aA1[r] + (1.0f / DELTA_F) * aB1[r];
        }
    }
    __syncthreads();   // all MFMA partials in hsf

    // ---- combine: h += x + bias, x = A*yraw_prev + B (BN'd residual) ----
    const int tx = tid & 15, ty = tid >> 4;
    const int o0 = tx * 4, n0 = ty * 2;
#pragma unroll
    for (int ni = 0; ni < 2; ++ni) {
        int n = n0 + ni;
        int node = pnod[n];
        float xa4[4] = {0.f, 0.f, 0.f, 0.f};
        if (node >= 0) {
            ushort4 hx = *(const ushort4*)(XHin + (size_t)node * DD + o0);
            xa4[0] = AFFS(o0 + 0) * bu2f(hx.x) + AFFB(o0 + 0);
            xa4[1] = AFFS(o0 + 1) * bu2f(hx.y) + AFFB(o0 + 1);
            xa4[2] = AFFS(o0 + 2) * bu2f(hx.z) + AFFB(o0 + 2);
            xa4[3] = AFFS(o0 + 3) * bu2f(hx.w) + AFFB(o0 + 3);
        }
#pragma unroll
        for (int oi = 0; oi < 4; ++oi) {
            int idx = (o0 + oi) * 34 + n;
            hsf[idx] = hsf[idx] + xa4[oi] + MBIAS(o0 + oi);
        }
    }
    __syncthreads();

    // ---- Lin1 (MFMA, hi/lo): A = h from hsf, W = Wlin frags; relu ----
    {
        floatx4 lacc[2];
        lacc[0] = (floatx4){0.f, 0.f, 0.f, 0.f};
        lacc[1] = (floatx4){0.f, 0.f, 0.f, 0.f};
#pragma unroll
        for (int kb = 0; kb < 2; ++kb) {
            short8 ah, al;
#pragma unroll
            for (int j = 0; j < 8; ++j) {
                float v = hsf[(kb * 32 + quad * 8 + j) * 34 + mtile * 16 + l16];
                ushort h = f2bu(v);
                ah[j] = (short)h;
                al[j] = (short)f2bu(v - bu2f(h));
            }
#pragma unroll
            for (int nti = 0; nti < 2; ++nti) {
                const int boff = ((kb * 4 + nt0 + nti) * 512) + ln * 8;
                short8 wh = *(const short8*)(Wlin + boff);
                short8 wl = *(const short8*)(Wlin + 4096 + boff);
                lacc[nti] = __builtin_amdgcn_mfma_f32_16x16x32_bf16(ah, wh, lacc[nti], 0, 0, 0);
                lacc[nti] = __builtin_amdgcn_mfma_f32_16x16x32_bf16(al, wh, lacc[nti], 0, 0, 0);
                lacc[nti] = __builtin_amdgcn_mfma_f32_16x16x32_bf16(ah, wl, lacc[nti], 0, 0, 0);
            }
        }
        __syncthreads();   // all A-reads done before overwriting hsf
#pragma unroll
        for (int nti = 0; nti < 2; ++nti) {
            int o = (nt0 + nti) * 16 + l16;
#pragma unroll
            for (int r = 0; r < 4; ++r)
                hsf[o * 34 + mtile * 16 + quad * 4 + r] = fmaxf(lacc[nti][r] + B1V(o), 0.f);
        }
    }
    __syncthreads();

    // ---- Lin2 (MFMA, hi/lo) + outer relu ----
    {
        floatx4 lacc[2];
        lacc[0] = (floatx4){0.f, 0.f, 0.f, 0.f};
        lacc[1] = (floatx4){0.f, 0.f, 0.f, 0.f};
#pragma unroll
        for (int kb = 0; kb < 2; ++kb) {
            short8 ah, al;
#pragma unroll
            for (int j = 0; j < 8; ++j) {
                float v = hsf[(kb * 32 + quad * 8 + j) * 34 + mtile * 16 + l16];
                ushort h = f2bu(v);
                ah[j] = (short)h;
                al[j] = (short)f2bu(v - bu2f(h));
            }
#pragma unroll
            for (int nti = 0; nti < 2; ++nti) {
                const int boff = ((kb * 4 + nt0 + nti) * 512) + ln * 8;
                short8 wh = *(const short8*)(Wlin + 8192 + boff);
                short8 wl = *(const short8*)(Wlin + 12288 + boff);
                lacc[nti] = __builtin_amdgcn_mfma_f32_16x16x32_bf16(ah, wh, lacc[nti], 0, 0, 0);
                lacc[nti] = __builtin_amdgcn_mfma_f32_16x16x32_bf16(al, wh, lacc[nti], 0, 0, 0);
                lacc[nti] = __builtin_amdgcn_mfma_f32_16x16x32_bf16(ah, wl, lacc[nti], 0, 0, 0);
            }
        }
        __syncthreads();
#pragma unroll
        for (int nti = 0; nti < 2; ++nti) {
            int o = (nt0 + nti) * 16 + l16;
#pragma unroll
            for (int r = 0; r < 4; ++r)
                hsf[o * 34 + mtile * 16 + quad * 4 + r] = fmaxf(lacc[nti][r] + B2V(o), 0.f);
        }
    }
    __syncthreads();

    // ---- write XHout (bf16) from hsf ----
    if (XHout) {
#pragma unroll
        for (int ni = 0; ni < 2; ++ni) {
            int n = n0 + ni;
            int node = pnod[n];
            if (node >= 0) {
                ushort4 h;
                h.x = f2bu(hsf[(o0 + 0) * 34 + n]);
                h.y = f2bu(hsf[(o0 + 1) * 34 + n]);
                h.z = f2bu(hsf[(o0 + 2) * 34 + n]);
                h.w = f2bu(hsf[(o0 + 3) * 34 + n]);
                *(ushort4*)(XHout + (size_t)node * DD + o0) = h;
            }
        }
    }

    // ---- BN partial sums (raw pre-BN y; order-free over valid columns) ----
    if (tid < 64) {
        float s = 0.f, sq = 0.f;
        int lim = NN - node0;
        if (lim > 32) lim = 32;
        for (int n = 0; n < lim; ++n) {
            float v = hsf[tid * 34 + n];
            s += v;
            sq += v * v;
        }
        atomicAdd(&bnstat[tid], s);
        atomicAdd(&bnstat[64 + tid], sq);
    }
}

// ---------------- pool: raw-sum layer-3 bf16 y into gpool (sorted batch) -------------
__global__ __launch_bounds__(256) void k_pool3(
    const ushort* __restrict__ YH, const int* __restrict__ batch,
    float* __restrict__ gpool) {
    __shared__ float pool[512];
    int tid = threadIdx.x;
    int i = blockIdx.x * 256 + tid;  // 8B-chunk index (4 feats)
    int n = i >> 4, fq = (i & 15) * 4;
    float4 r = make_float4(0.f, 0.f, 0.f, 0.f);
    bool valid = i < NN * 16;
    if (valid) {
        ushort4 h = *(const ushort4*)(YH + (size_t)n * DD + fq);
        r.x = bu2f(h.x); r.y = bu2f(h.y); r.z = bu2f(h.z); r.w = bu2f(h.w);
    }
    int nfirst = blockIdx.x * 16;
    int nlast = nfirst + 15;
    if (nlast >= NN) nlast = NN - 1;
    int gmin = batch[nfirst], gmax = batch[nlast];
    int span = gmax - gmin + 1;
    if (span <= 8) {
        for (int j = tid; j < span * 64; j += 256) pool[j] = 0.f;
        __syncthreads();
        if (valid) {
            int gb = batch[n] - gmin;
            atomicAdd(&pool[gb * 64 + fq + 0], r.x);
            atomicAdd(&pool[gb * 64 + fq + 1], r.y);
            atomicAdd(&pool[gb * 64 + fq + 2], r.z);
            atomicAdd(&pool[gb * 64 + fq + 3], r.w);
        }
        __syncthreads();
        for (int j = tid; j < span * 64; j += 256)
            atomicAdd(&gpool[(size_t)(gmin + (j >> 6)) * 64 + (j & 63)], pool[j]);
    } else {
        if (valid) {
            float* gp = gpool + (size_t)batch[n] * DD + fq;
            atomicAdd(gp + 0, r.x);
            atomicAdd(gp + 1, r.y);
            atomicAdd(gp + 2, r.z);
            atomicAdd(gp + 3, r.w);
        }
    }
}

// ---------------- head: BN3-affine on raw pool, fc1+relu, fc2, log_softmax ----------
__global__ __launch_bounds__(256) void k_head(const float* __restrict__ gpool,
                                              const float* __restrict__ bs3,
                                              const float* __restrict__ g3,
                                              const float* __restrict__ b3,
                                              const int* __restrict__ gcnt,
                                              const float* __restrict__ fc1W, const float* __restrict__ fc1b,
                                              const float* __restrict__ fc2W, const float* __restrict__ fc2b,
                                              float* __restrict__ out) {
    __shared__ float sh[12640];
    float* const gs = sh;
    float* const w1t = sh + 4096;
    float* const z1s = sh + 8256;
    float* const b1s = sh + 12416;
    float* const b2s = sh + 12480;
    float* const sc3 = sh + 12512;
    float* const shf3 = sh + 12576;
    float* const w2t = sh;
    float* const z2s = sh + 4096;

    int tid = threadIdx.x;
    if (tid < 64) {
        float mean = bs3[tid] * (1.f / NN);
        float var = fmaxf(bs3[64 + tid] * (1.f / NN) - mean * mean, 0.f);
        float inv = rsqrtf(var + BN_EPS_F);
        float A = g3[tid] * inv;
        sc3[tid] = A;
        shf3[tid] = b3[tid] - mean * A;
    }
    __syncthreads();
    for (int i = tid; i < 4096; i += 256) {
        int o = i >> 6, j = i & 63;
        gs[i] = sc3[j] * gpool[i] + shf3[j] * (float)gcnt[o];
        w1t[j * 65 + o] = fc1W[i];
    }
    if (tid < 64) b1s[tid] = fc1b[tid];
    if (tid < 32) b2s[tid] = fc2b[tid];
    __syncthreads();
    {
        int tx = tid & 15, ty = tid >> 4, o0 = tx * 4, g0 = ty * 4;
        float acc[16];
#pragma unroll
        for (int i = 0; i < 16; ++i) acc[i] = 0.f;
        for (int j = 0; j < 64; ++j) {
            float w0 = w1t[j * 65 + o0 + 0], w1 = w1t[j * 65 + o0 + 1];
            float w2 = w1t[j * 65 + o0 + 2], w3 = w1t[j * 65 + o0 + 3];
#pragma unroll
            for (int gi = 0; gi < 4; ++gi) {
                float a = gs[(g0 + gi) * 64 + j];
                acc[gi * 4 + 0] += a * w0; acc[gi * 4 + 1] += a * w1;
                acc[gi * 4 + 2] += a * w2; acc[gi * 4 + 3] += a * w3;
            }
        }
        __syncthreads();
#pragma unroll
        for (int gi = 0; gi < 4; ++gi)
#pragma unroll
            for (int oi = 0; oi < 4; ++oi)
                z1s[(g0 + gi) * 65 + o0 + oi] = fmaxf(acc[gi * 4 + oi] + b1s[o0 + oi], 0.f);
    }
    for (int i = tid; i < 2048; i += 256) {
        int o = i >> 6, j = i & 63;
        w2t[j * 33 + o] = fc2W[i];
    }
    __syncthreads();
    {
        int tx = tid & 7, ty = tid >> 3, o0 = tx * 4, g0 = ty * 2;
        float acc[8];
#pragma unroll
        for (int i = 0; i < 8; ++i) acc[i] = 0.f;
        for (int j = 0; j < 64; ++j) {
            float w0 = w2t[j * 33 + o0 + 0], w1 = w2t[j * 33 + o0 + 1];
            float w2 = w2t[j * 33 + o0 + 2], w3 = w2t[j * 33 + o0 + 3];
            float a0 = z1s[(g0 + 0) * 65 + j];
            float a1 = z1s[(g0 + 1) * 65 + j];
            acc[0] += a0 * w0; acc[1] += a0 * w1; acc[2] += a0 * w2; acc[3] += a0 * w3;
            acc[4] += a1 * w0; acc[5] += a1 * w1; acc[6] += a1 * w2; acc[7] += a1 * w3;
        }
#pragma unroll
        for (int gi = 0; gi < 2; ++gi)
#pragma unroll
            for (int oi = 0; oi < 4; ++oi)
                z2s[(g0 + gi) * 33 + o0 + oi] = acc[gi * 4 + oi] + b2s[o0 + oi];
    }
    __syncthreads();
    if (tid < 64) {
        float m = -3.402823466e38f;
        for (int c = 0; c < DOUT; ++c) m = fmaxf(m, z2s[tid * 33 + c]);
        float s = 0.f;
        for (int c = 0; c < DOUT; ++c) s += expf(z2s[tid * 33 + c] - m);
        float lse = m + logf(s);
        for (int c = 0; c < DOUT; ++c)
            out[tid * DOUT + c] = z2s[tid * 33 + c] - lse;
    }
}

extern "C" void kernel_launch(void* const* d_in, const int* in_sizes, int n_in,
                              void* d_out, int out_size, void* d_ws, size_t ws_size,
                              hipStream_t stream) {
    const float* x = (const float*)d_in[0];
    const int* ei = (const int*)d_in[1];
    const int* src = ei;
    const int* dst = ei + NE;
    const int* batch = (const int*)d_in[2];
    const float *mlpW[3], *mlpB[3], *w1[3], *bb1[3], *w2[3], *bb2[3], *bng[3], *bnb[3];
    for (int l = 0; l < 3; ++l) {
        mlpW[l] = (const float*)d_in[3 + 6 * l];
        mlpB[l] = (const float*)d_in[4 + 6 * l];
        w1[l]   = (const float*)d_in[5 + 6 * l];
        bb1[l]  = (const float*)d_in[6 + 6 * l];
        w2[l]   = (const float*)d_in[7 + 6 * l];
        bb2[l]  = (const float*)d_in[8 + 6 * l];
        bng[l]  = (const float*)d_in[21 + 2 * l];
        bnb[l]  = (const float*)d_in[22 + 2 * l];
    }
    const float* fc1W = (const float*)d_in[27];
    const float* fc1b = (const float*)d_in[28];
    const float* fc2W = (const float*)d_in[29];
    const float* fc2b = (const float*)d_in[30];
    float* out = (float*)d_out;

    char* ws = (char*)d_ws;
    size_t off = 0;
    auto alloc = [&](size_t bytes) -> void* {
        void* p = ws + off;
        off = (off + bytes + 511) & ~(size_t)511;
        return p;
    };
    int* counts    = (int*)alloc((size_t)NN * 4);
    int* row_ptr   = (int*)alloc((size_t)(NN + 1) * 4);
    int* rank      = (int*)alloc((size_t)NE * 4);
    int* blockSums = (int*)alloc(256 * 4);
    int* blockBase = (int*)alloc(256 * 4);
    int* csr_src   = (int*)alloc((size_t)NE * 4);
    int* blockHist = (int*)alloc((size_t)196 * 256 * 4);
    int* binTot    = (int*)alloc(256 * 4);
    int* binBase   = (int*)alloc(256 * 4);
    int* perm      = (int*)alloc((size_t)NN * 4);
    ushort* XHA    = (ushort*)alloc((size_t)NN * DD * 2);
    ushort* XHB    = (ushort*)alloc((size_t)NN * DD * 2);
    ushort* Wb     = (ushort*)alloc((size_t)3 * 65536 * 2);
    ushort* Wsb    = (ushort*)alloc((size_t)3 * 16384 * 2);
    float* bnstat  = (float*)alloc(384 * 4);
    float* gpool   = (float*)alloc((size_t)NGRAPH * DD * 4);
    int* gcnt      = (int*)alloc(NGRAPH * 4);
    (void)ws_size; (void)in_sizes; (void)n_in; (void)out_size;

    k_prep<<<3125, 256, 0, stream>>>(x, XHA,
                                     mlpW[0], mlpW[1], mlpW[2],
                                     w1[0], w2[0], w1[1], w2[1], w1[2], w2[2],
                                     Wb, Wsb, counts, bnstat, gpool);
    k_rank<<<1563, 256, 0, stream>>>(dst, counts, rank);
    k_scan_a<<<196, 256, 0, stream>>>(counts, blockSums, blockHist);
    k_dscanA<<<256, 256, 0, stream>>>(blockHist, binTot);
    k_scan_b<<<1, 256, 0, stream>>>(blockSums, blockBase, batch, gcnt, binTot, binBase);
    k_scan_c<<<196, 256, 0, stream>>>(counts, blockBase, row_ptr);
    k_place<<<1563, 256, 0, stream>>>(src, dst, rank, row_ptr, csr_src);
    k_dplace<<<196, 256, 0, stream>>>(counts, blockHist, binBase, perm);

    // layer 1: in XHA (identity affine), out XHB (raw bf16 y)
    k_fused<<<1563, 256, 0, stream>>>(XHA, XHB, perm, row_ptr, csr_src,
                                      Wb, Wsb, mlpB[0], bb1[0], bb2[0],
                                      nullptr, nullptr, nullptr,
                                      bnstat);
    // layer 2: in XHB (affine from bnstat[0]), out XHA
    k_fused<<<1563, 256, 0, stream>>>(XHB, XHA, perm, row_ptr, csr_src,
                                      Wb + 65536, Wsb + 16384, mlpB[1], bb1[1], bb2[1],
                                      bnstat, bng[0], bnb[0],
                                      bnstat + 128);
    // layer 3: in XHA (affine from bnstat[1]), out XHB (raw bf16 y)
    k_fused<<<1563, 256, 0, stream>>>(XHA, XHB, perm, row_ptr, csr_src,
                                      Wb + 2 * 65536, Wsb + 2 * 16384, mlpB[2], bb1[2], bb2[2],
                                      bnstat + 128, bng[1], bnb[1],
                                      bnstat + 256);
    k_pool3<<<3125, 256, 0, stream>>>(XHB, batch, gpool);
    k_head<<<1, 256, 0, stream>>>(gpool, bnstat + 256, bng[2], bnb[2], gcnt,
                                  fc1W, fc1b, fc2W, fc2b, out);
}

// Round 13
// 454.867 us; speedup vs baseline: 1.0735x; 1.0434x over previous
//
#include <hip/hip_runtime.h>

#define NN 50000
#define NE 1600000
#define DD 64
#define NGRAPH 64
#define DOUT 32
#define DELTA_F 2.5749f
#define BN_EPS_F 1e-5f

typedef unsigned short ushort;
typedef __attribute__((ext_vector_type(8))) short short8;
typedef __attribute__((ext_vector_type(4))) float floatx4;

static __device__ __forceinline__ float blo(unsigned u) {
    return __uint_as_float(u << 16);
}
static __device__ __forceinline__ float bhi(unsigned u) {
    return __uint_as_float(u & 0xFFFF0000u);
}
static __device__ __forceinline__ float bu2f(ushort u) {
    return __uint_as_float(((unsigned)u) << 16);
}
static __device__ __forceinline__ ushort f2bu(float f) {
    unsigned u = __float_as_uint(f);
    unsigned r = (u + 0x7FFF + ((u >> 16) & 1)) >> 16;   // round-to-nearest-even
    return (ushort)r;
}
static __device__ __forceinline__ unsigned pk(float a, float b) {
    return ((unsigned)f2bu(b) << 16) | (unsigned)f2bu(a);
}

// ---------------- prep: init + x->bf16 + weight prep (fused, 1 launch) ----------------
__global__ void k_prep(const float* __restrict__ x, ushort* __restrict__ XH,
                       const float* __restrict__ w0, const float* __restrict__ w1,
                       const float* __restrict__ w2,
                       const float* __restrict__ a0, const float* __restrict__ a1,
                       const float* __restrict__ a2, const float* __restrict__ a3,
                       const float* __restrict__ a4, const float* __restrict__ a5,
                       ushort* __restrict__ Wb, ushort* __restrict__ Wsb,
                       int* __restrict__ counts, float* __restrict__ bnstat,
                       float* __restrict__ gpool) {
    int i = blockIdx.x * 256 + threadIdx.x;
    if (i < NN) counts[i] = 0;
    if (i < 384) bnstat[i] = 0.f;
    if (i < NGRAPH * DD) gpool[i] = 0.f;
    if (i < NN * 16) {
        float4 v = *(const float4*)(x + (size_t)i * 4);
        ushort4 h;
        h.x = f2bu(v.x); h.y = f2bu(v.y); h.z = f2bu(v.z); h.w = f2bu(v.w);
        *(ushort4*)(XH + (size_t)i * 4) = h;
    }
    if (i < 3 * 65536) {
        int layer = i / 65536, r = i % 65536;
        const float* w = (layer == 0) ? w0 : ((layer == 1) ? w1 : w2);
        int c = r / 16384, r2 = r % 16384;
        int kb = r2 >> 11, r3 = r2 & 2047;
        int t = r3 >> 9, r4 = r3 & 511;
        int l = r4 >> 3, j = r4 & 7;
        int k = kb * 32 + (l >> 4) * 8 + j;
        int o = t * 16 + (l & 15);
        int g = (c == 0) ? 0 : ((c == 3) ? 2 : 1);
        float wv = w[o * 768 + g * 256 + k];
        ushort h = f2bu(wv);
        Wb[i] = (c == 2) ? f2bu(wv - bu2f(h)) : h;
    } else if (i < 3 * 65536 + 3 * 16384) {
        int i2 = i - 3 * 65536;
        int layer = i2 / 16384, r = i2 % 16384;
        int lin = r >> 13, r2 = r & 8191;
        int hl = r2 >> 12, r3 = r2 & 4095;
        int kb = r3 >> 11, r4 = r3 & 2047;
        int t = r4 >> 9, r5 = r4 & 511;
        int l = r5 >> 3, j = r5 & 7;
        int k = kb * 32 + (l >> 4) * 8 + j;
        int o = t * 16 + (l & 15);
        const float* w = (lin == 0)
            ? ((layer == 0) ? a0 : (layer == 1) ? a2 : a4)
            : ((layer == 0) ? a1 : (layer == 1) ? a3 : a5);
        float wv = w[o * 64 + k];
        ushort h = f2bu(wv);
        Wsb[i2] = hl ? f2bu(wv - bu2f(h)) : h;
    }
}

// ---------------- CSR build (rank/scan/place — single atomic pass, int4 loads) --------
__global__ void k_rank(const int* __restrict__ dst, int* __restrict__ counts,
                       int* __restrict__ rank) {
    int i = blockIdx.x * 256 + threadIdx.x;
    if (i < NE / 4) {
        int4 d = ((const int4*)dst)[i];
        int4 r;
        r.x = atomicAdd(&counts[d.x], 1);
        r.y = atomicAdd(&counts[d.y], 1);
        r.z = atomicAdd(&counts[d.z], 1);
        r.w = atomicAdd(&counts[d.w], 1);
        ((int4*)rank)[i] = r;
    }
}

// block-sum reduction + degree histogram (counts[gid] = degree after k_rank)
__global__ void k_scan_a(const int* __restrict__ counts, int* __restrict__ blockSums,
                         int* __restrict__ BH) {
    __shared__ int red[256];
    __shared__ int h[256];
    int tid = threadIdx.x;
    h[tid] = 0;
    int gid = blockIdx.x * 256 + tid;
    int v = (gid < NN) ? counts[gid] : 0;
    red[tid] = v;
    __syncthreads();
    if (gid < NN) {
        int d = (v > 255) ? 255 : v;
        atomicAdd(&h[d], 1);
    }
    for (int s = 128; s > 0; s >>= 1) {
        if (tid < s) red[tid] += red[tid + s];
        __syncthreads();
    }
    if (tid == 0) blockSums[blockIdx.x] = red[0];
    BH[blockIdx.x * 256 + tid] = h[tid];
}

// merged: blocks 0..255 = per-bin exclusive prefix over the 196 blocks (dscanA);
//         block 256     = blockBase scan + gcnt binary search (old scan_b).
__global__ void k_scanB2(int* __restrict__ BH, int* __restrict__ binTot,
                         const int* __restrict__ blockSums, int* __restrict__ blockBase,
                         const int* __restrict__ batch, int* __restrict__ gcnt) {
    __shared__ int sh[256];
    int t = threadIdx.x;
    if (blockIdx.x < 256) {
        int b = blockIdx.x;
        int v = (t < 196) ? BH[t * 256 + b] : 0;
        sh[t] = v;
        __syncthreads();
        for (int off = 1; off < 256; off <<= 1) {
            int tv = (t >= off) ? sh[t - off] : 0;
            __syncthreads();
            sh[t] += tv;
            __syncthreads();
        }
        if (t < 196) BH[t * 256 + b] = sh[t] - v;   // exclusive along blocks
        if (t == 255) binTot[b] = sh[255];
    } else {
        int v = (t < 196) ? blockSums[t] : 0;
        sh[t] = v;
        __syncthreads();
        for (int off = 1; off < 256; off <<= 1) {
            int tv = (t >= off) ? sh[t - off] : 0;
            __syncthreads();
            sh[t] += tv;
            __syncthreads();
        }
        blockBase[t] = sh[t] - v;  // exclusive
        if (t < NGRAPH) {
            auto lb = [&](int g) {
                int lo = 0, hi = NN;
                while (lo < hi) {
                    int mid = (lo + hi) >> 1;
                    if (batch[mid] < g) lo = mid + 1; else hi = mid;
                }
                return lo;
            };
            gcnt[t] = lb(t + 1) - lb(t);
        }
    }
}

// merged: row_ptr scan (old scan_c) + degree-sorted perm placement (old dplace).
// binBase recomputed locally from binTot via a 256-wide LDS scan (~free).
__global__ void k_scanC2(const int* __restrict__ counts, const int* __restrict__ blockBase,
                         int* __restrict__ row_ptr,
                         const int* __restrict__ BH, const int* __restrict__ binTot,
                         int* __restrict__ perm) {
    __shared__ int sh[256];
    __shared__ int h2[256];
    __shared__ int bb[256];
    int tid = threadIdx.x;
    int gid = blockIdx.x * 256 + tid;
    int v = (gid < NN) ? counts[gid] : 0;
    sh[tid] = v;
    h2[tid] = 0;
    __syncthreads();
    for (int off = 1; off < 256; off <<= 1) {
        int t = (tid >= off) ? sh[tid - off] : 0;
        __syncthreads();
        sh[tid] += t;
        __syncthreads();
    }
    int excl = blockBase[blockIdx.x] + sh[tid] - v;
    if (gid <= NN) row_ptr[gid] = excl;
    __syncthreads();   // done with sh (row_ptr scan)
    int bt = binTot[tid];
    sh[tid] = bt;
    __syncthreads();
    for (int off = 1; off < 256; off <<= 1) {
        int t = (tid >= off) ? sh[tid - off] : 0;
        __syncthreads();
        sh[tid] += t;
        __syncthreads();
    }
    bb[tid] = (sh[tid] - bt) + BH[blockIdx.x * 256 + tid];   // binBase + block offset
    __syncthreads();
    if (gid < NN) {
        int d = (v > 255) ? 255 : v;
        int lr = atomicAdd(&h2[d], 1);
        perm[bb[d] + lr] = gid;
    }
}

__global__ void k_place(const int* __restrict__ src, const int* __restrict__ dst,
                        const int* __restrict__ rank, const int* __restrict__ row_ptr,
                        int* __restrict__ csr_src) {
    int i = blockIdx.x * 256 + threadIdx.x;
    if (i < NE / 4) {
        int4 s4 = ((const int4*)src)[i];
        int4 d4 = ((const int4*)dst)[i];
        int4 r4 = ((const int4*)rank)[i];
        csr_src[row_ptr[d4.x] + r4.x] = s4.x;
        csr_src[row_ptr[d4.y] + r4.y] = s4.y;
        csr_src[row_ptr[d4.z] + r4.z] = s4.z;
        csr_src[row_ptr[d4.w] + r4.w] = s4.w;
    }
}

// ======================================================================
// Fused layer (R12 core): Ntile=32, 256 threads, MFMA mlp GEMM (g=1 hi/lo)
// + MFMA Lin1/Lin2 (hi/lo), BN folded into gather stats, no VGPR spill.
// Two verified orderings:
//   perm != NULL: degree-sorted (71us/layer measured), no pooling.
//   perm == NULL: identity order (R10, 77us) + fused raw pool (layer 3) —
//                 batch-sorted runs make the segment-atomic pool cheap.
// LDS: Agh[32][200] | Agl[32][200] | aux[352] | pnod[32] | ibatch[32]
// ======================================================================
#define MBIAS(i) aux[i]
#define B1V(i)   aux[64 + (i)]
#define B2V(i)   aux[128 + (i)]
#define DEGV(m)  aux[192 + (m)]
#define AFFS(i)  aux[224 + (i)]
#define AFFB(i)  aux[288 + (i)]

__global__ __launch_bounds__(256, 4) void k_fused(
    const ushort* __restrict__ XHin, ushort* __restrict__ XHout,
    const int* __restrict__ perm,
    const int* __restrict__ row_ptr, const int* __restrict__ csr_src,
    const ushort* __restrict__ Wbh, const ushort* __restrict__ Wlin,
    const float* __restrict__ mlp_b,
    const float* __restrict__ b1, const float* __restrict__ b2,
    const float* __restrict__ affstat, const float* __restrict__ affg,
    const float* __restrict__ affb,
    float* __restrict__ bnstat,
    const int* __restrict__ batch, float* __restrict__ gpool, int do_pool) {
    __shared__ __align__(16) char smem[27264];
    ushort* const Agh = (ushort*)smem;                // 32 x 200 bf16 = 12800 B
    ushort* const Agl = (ushort*)(smem + 12800);      // 32 x 200 bf16 = 12800 B
    float* const aux = (float*)(smem + 25600);        // 352 f32
    int* const pnod = (int*)(smem + 27008);           // 32 ints
    int* const ibatch = (int*)(smem + 27136);         // 32 ints
    float* const hsf = (float*)smem;                  // overlays Agh (64x34 f32 = 8704 B)

    const int tid = threadIdx.x;
    const int node0 = blockIdx.x * 32;

    if (tid < 64) {
        MBIAS(tid) = mlp_b[tid];
        B1V(tid) = b1[tid];
        B2V(tid) = b2[tid];
        float A = 1.f, Bv = 0.f;
        if (affstat) {
            float mean = affstat[tid] * (1.f / NN);
            float var = fmaxf(affstat[64 + tid] * (1.f / NN) - mean * mean, 0.f);
            float inv = rsqrtf(var + BN_EPS_F);
            A = affg[tid] * inv;           // > 0 (bn gamma = 1)
            Bv = affb[tid] - mean * A;
        }
        AFFS(tid) = A;
        AFFB(tid) = Bv;
    }
    if (tid < 32) {
        int sl = node0 + tid;
        int nd = (sl < NN) ? (perm ? perm[sl] : sl) : -1;
        pnod[tid] = nd;
        ibatch[tid] = (do_pool && nd >= 0) ? batch[nd] : -1;
    }
    __syncthreads();   // AFFS/AFFB/pnod/ibatch visible

    // ---- gather: 32 groups of 8 lanes; 4-row double-buffered batches ----
    {
        const int l8 = tid & 7;
        const int m = tid >> 3;                // 0..31
        const int node = pnod[m];
        const int f0 = l8 * 8;
        const ushort* Xp = XHin + f0;

        float s[8], q[8], mx[8];
#pragma unroll
        for (int i = 0; i < 8; ++i) { s[i] = 0.f; q[i] = 0.f; mx[i] = -3.402823466e38f; }

        auto acc8 = [&](const uint4& rr) {
            float v0 = blo(rr.x), v1 = bhi(rr.x);
            float v2 = blo(rr.y), v3 = bhi(rr.y);
            float v4 = blo(rr.z), v5 = bhi(rr.z);
            float v6 = blo(rr.w), v7 = bhi(rr.w);
            s[0] += v0; q[0] = fmaf(v0, v0, q[0]); mx[0] = fmaxf(mx[0], v0);
            s[1] += v1; q[1] = fmaf(v1, v1, q[1]); mx[1] = fmaxf(mx[1], v1);
            s[2] += v2; q[2] = fmaf(v2, v2, q[2]); mx[2] = fmaxf(mx[2], v2);
            s[3] += v3; q[3] = fmaf(v3, v3, q[3]); mx[3] = fmaxf(mx[3], v3);
            s[4] += v4; q[4] = fmaf(v4, v4, q[4]); mx[4] = fmaxf(mx[4], v4);
            s[5] += v5; q[5] = fmaf(v5, v5, q[5]); mx[5] = fmaxf(mx[5], v5);
            s[6] += v6; q[6] = fmaf(v6, v6, q[6]); mx[6] = fmaxf(mx[6], v6);
            s[7] += v7; q[7] = fmaf(v7, v7, q[7]); mx[7] = fmaxf(mx[7], v7);
        };

        int beg = 0, end = 0;
        if (node >= 0) { beg = row_ptr[node]; end = row_ptr[node + 1]; }
        const int deg = end - beg;
        const int nb = (deg + 3) >> 2;

        uint4 ra[4], rb[4];
        int ia[4];
        if (nb > 0) {
#pragma unroll
            for (int j = 0; j < 4; ++j) {
                int e = beg + j;
                ia[j] = csr_src[(e < end) ? e : end - 1];
            }
#pragma unroll
            for (int j = 0; j < 4; ++j)
                ra[j] = *(const uint4*)(Xp + (size_t)ia[j] * 64);
            if (nb > 1) {
#pragma unroll
                for (int j = 0; j < 4; ++j) {
                    int e = beg + 4 + j;
                    ia[j] = csr_src[(e < end) ? e : end - 1];
                }
            }
        }
        for (int t = 0; t < nb; ++t) {
            if (t + 1 < nb) {
#pragma unroll
                for (int j = 0; j < 4; ++j)
                    rb[j] = *(const uint4*)(Xp + (size_t)ia[j] * 64);
            }
            if (t + 2 < nb) {
                int b2e = beg + (t + 2) * 4;
#pragma unroll
                for (int j = 0; j < 4; ++j) {
                    int e = b2e + j;
                    ia[j] = csr_src[(e < end) ? e : end - 1];
                }
            }
            int cnt = end - (beg + t * 4);
            if (cnt >= 4) {
#pragma unroll
                for (int j = 0; j < 4; ++j) acc8(ra[j]);
            } else {
#pragma unroll
                for (int j = 0; j < 4; ++j) if (j < cnt) acc8(ra[j]);
            }
            if (t + 1 < nb) {
#pragma unroll
                for (int j = 0; j < 4; ++j) ra[j] = rb[j];
            }
        }

        float cdeg = (node >= 0) ? (float)deg : 1.f;
        float rc = 1.0f / cdeg;
        float var[8];
#pragma unroll
        for (int i = 0; i < 8; ++i) {
            float mean = s[i] * rc;
            var[i] = fmaxf(q[i] * rc - mean * mean, 0.f);
            if (node < 0) { mx[i] = 0.f; var[i] = 0.f; }
        }
        // BN fold: stats of m = A*yraw + B from raw stats
#pragma unroll
        for (int i = 0; i < 8; ++i) {
            float Af = AFFS(f0 + i), Bf = AFFB(f0 + i);
            s[i] = Af * s[i] + cdeg * Bf;
            mx[i] = Af * mx[i] + Bf;
            var[i] = Af * Af * var[i];
        }
        // hi/lo bf16 stats -> Agh/Agl, [m][k] pitch 200
        ushort* dh = Agh + m * 200 + f0;
        ushort* dl = Agl + m * 200 + f0;
        auto emit8 = [&](const float* v, int off) {
            ushort h0 = f2bu(v[0]), h1 = f2bu(v[1]), h2 = f2bu(v[2]), h3 = f2bu(v[3]);
            ushort h4 = f2bu(v[4]), h5 = f2bu(v[5]), h6 = f2bu(v[6]), h7 = f2bu(v[7]);
            uint4 hv;
            hv.x = (unsigned)h0 | ((unsigned)h1 << 16);
            hv.y = (unsigned)h2 | ((unsigned)h3 << 16);
            hv.z = (unsigned)h4 | ((unsigned)h5 << 16);
            hv.w = (unsigned)h6 | ((unsigned)h7 << 16);
            uint4 lv;
            lv.x = pk(v[0] - bu2f(h0), v[1] - bu2f(h1));
            lv.y = pk(v[2] - bu2f(h2), v[3] - bu2f(h3));
            lv.z = pk(v[4] - bu2f(h4), v[5] - bu2f(h5));
            lv.w = pk(v[6] - bu2f(h6), v[7] - bu2f(h7));
            *(uint4*)(dh + off) = hv;
            *(uint4*)(dl + off) = lv;
        };
        emit8(s, 0);
        emit8(mx, 64);
        emit8(var, 128);
        if (l8 == 0) DEGV(m) = cdeg;
    }
    __syncthreads();

    // ---- load MFMA A hi fragments only (lo read on demand from live Agl) ----
    const int ln = tid & 63, wvi = tid >> 6;
    const int quad = ln >> 4, l16 = ln & 15;
    const int mtile = wvi >> 1;          // 0..1
    const int nt0 = (wvi & 1) * 2;       // ntiles nt0, nt0+1

    const ushort* ArowH = Agh + (mtile * 16 + l16) * 200 + quad * 8;
    const ushort* ArowL = Agl + (mtile * 16 + l16) * 200 + quad * 8;
    short8 afh[6];
#pragma unroll
    for (int i = 0; i < 6; ++i) {
        const int off = (i >> 1) * 64 + (i & 1) * 32;   // 0,32,64,96,128,160
        afh[i] = *(const short8*)(ArowH + off);
    }
    __syncthreads();   // Agh frag reads done -> hsf (Agh overlay) writable.
                       // Agl (bytes 12800+) is NOT overlaid -> lo frags read in-loop.

    // ---- MFMA: all three g-chunks; g=1 in hi/lo (3 MFMA per amplified kb) ----
#pragma unroll
    for (int nti = 0; nti < 2; ++nti) {
        const int nt = nt0 + nti;
        floatx4 aA0 = (floatx4){0.f, 0.f, 0.f, 0.f};
        floatx4 aB0 = (floatx4){0.f, 0.f, 0.f, 0.f};
        floatx4 aA1 = (floatx4){0.f, 0.f, 0.f, 0.f};
        floatx4 aB1 = (floatx4){0.f, 0.f, 0.f, 0.f};
        floatx4 aA2 = (floatx4){0.f, 0.f, 0.f, 0.f};
        floatx4 aB2 = (floatx4){0.f, 0.f, 0.f, 0.f};
#pragma unroll
        for (int kb = 0; kb < 8; ++kb) {
            const int am = (kb < 4) ? kb : ((kb < 6) ? (kb - 4) : (kb - 2));
            const int base = ((kb * 4 + nt) * 512) + ln * 8;
            short8 w0 = *(const short8*)(Wbh + base);                 // g=0
            short8 w1h = *(const short8*)(Wbh + 16384 + base);        // g=1 hi
            short8 w2 = *(const short8*)(Wbh + 3 * 16384 + base);     // g=2
            if (kb == 4 || kb == 5) {
                aB0 = __builtin_amdgcn_mfma_f32_16x16x32_bf16(afh[am], w0, aB0, 0, 0, 0);
                aB1 = __builtin_amdgcn_mfma_f32_16x16x32_bf16(afh[am], w1h, aB1, 0, 0, 0);
                aB2 = __builtin_amdgcn_mfma_f32_16x16x32_bf16(afh[am], w2, aB2, 0, 0, 0);
            } else {
                short8 w1l = *(const short8*)(Wbh + 2 * 16384 + base);  // g=1 lo
                short8 al = *(const short8*)(ArowL + ((am >> 1) * 64 + (am & 1) * 32));
                aA0 = __builtin_amdgcn_mfma_f32_16x16x32_bf16(afh[am], w0, aA0, 0, 0, 0);
                aA1 = __builtin_amdgcn_mfma_f32_16x16x32_bf16(afh[am], w1h, aA1, 0, 0, 0);
                aA1 = __builtin_amdgcn_mfma_f32_16x16x32_bf16(al, w1h, aA1, 0, 0, 0);
                aA1 = __builtin_amdgcn_mfma_f32_16x16x32_bf16(afh[am], w1l, aA1, 0, 0, 0);
                aA2 = __builtin_amdgcn_mfma_f32_16x16x32_bf16(afh[am], w2, aA2, 0, 0, 0);
            }
        }
        // partial -> hsf[n][m]
#pragma unroll
        for (int r = 0; r < 4; ++r) {
            int m = mtile * 16 + quad * 4 + r;
            float dg = DEGV(m), rcd = 1.f / dg;
            float cA2 = DELTA_F * rcd;
            float cB2 = DELTA_F * rcd * rcd;
            float cA1 = dg * (1.0f / DELTA_F);
            int n = nt * 16 + l16;
            hsf[n * 34 + m] = aA0[r] + rcd * aB0[r]
                            + cA2 * aA2[r] + cB2 * aB2[r]
                            + cA1 * aA1[r] + (1.0f / DELTA_F) * aB1[r];
        }
    }
    __syncthreads();   // all MFMA partials in hsf

    // ---- combine: h += x + bias, x = A*yraw_prev + B (BN'd residual) ----
    const int tx = tid & 15, ty = tid >> 4;
    const int o0 = tx * 4, n0 = ty * 2;
#pragma unroll
    for (int ni = 0; ni < 2; ++ni) {
        int n = n0 + ni;
        int node = pnod[n];
        float xa4[4] = {0.f, 0.f, 0.f, 0.f};
        if (node >= 0) {
            ushort4 hx = *(const ushort4*)(XHin + (size_t)node * DD + o0);
            xa4[0] = AFFS(o0 + 0) * bu2f(hx.x) + AFFB(o0 + 0);
            xa4[1] = AFFS(o0 + 1) * bu2f(hx.y) + AFFB(o0 + 1);
            xa4[2] = AFFS(o0 + 2) * bu2f(hx.z) + AFFB(o0 + 2);
            xa4[3] = AFFS(o0 + 3) * bu2f(hx.w) + AFFB(o0 + 3);
        }
#pragma unroll
        for (int oi = 0; oi < 4; ++oi) {
            int idx = (o0 + oi) * 34 + n;
            hsf[idx] = hsf[idx] + xa4[oi] + MBIAS(o0 + oi);
        }
    }
    __syncthreads();

    // ---- Lin1 (MFMA, hi/lo): A = h from hsf, W = Wlin frags; relu ----
    {
        floatx4 lacc[2];
        lacc[0] = (floatx4){0.f, 0.f, 0.f, 0.f};
        lacc[1] = (floatx4){0.f, 0.f, 0.f, 0.f};
#pragma unroll
        for (int kb = 0; kb < 2; ++kb) {
            short8 ah, al;
#pragma unroll
            for (int j = 0; j < 8; ++j) {
                float v = hsf[(kb * 32 + quad * 8 + j) * 34 + mtile * 16 + l16];
                ushort h = f2bu(v);
                ah[j] = (short)h;
                al[j] = (short)f2bu(v - bu2f(h));
            }
#pragma unroll
            for (int nti = 0; nti < 2; ++nti) {
                const int boff = ((kb * 4 + nt0 + nti) * 512) + ln * 8;
                short8 wh = *(const short8*)(Wlin + boff);
                short8 wl = *(const short8*)(Wlin + 4096 + boff);
                lacc[nti] = __builtin_amdgcn_mfma_f32_16x16x32_bf16(ah, wh, lacc[nti], 0, 0, 0);
                lacc[nti] = __builtin_amdgcn_mfma_f32_16x16x32_bf16(al, wh, lacc[nti], 0, 0, 0);
                lacc[nti] = __builtin_amdgcn_mfma_f32_16x16x32_bf16(ah, wl, lacc[nti], 0, 0, 0);
            }
        }
        __syncthreads();   // all A-reads done before overwriting hsf
#pragma unroll
        for (int nti = 0; nti < 2; ++nti) {
            int o = (nt0 + nti) * 16 + l16;
#pragma unroll
            for (int r = 0; r < 4; ++r)
                hsf[o * 34 + mtile * 16 + quad * 4 + r] = fmaxf(lacc[nti][r] + B1V(o), 0.f);
        }
    }
    __syncthreads();

    // ---- Lin2 (MFMA, hi/lo) + outer relu ----
    {
        floatx4 lacc[2];
        lacc[0] = (floatx4){0.f, 0.f, 0.f, 0.f};
        lacc[1] = (floatx4){0.f, 0.f, 0.f, 0.f};
#pragma unroll
        for (int kb = 0; kb < 2; ++kb) {
            short8 ah, al;
#pragma unroll
            for (int j = 0; j < 8; ++j) {
                float v = hsf[(kb * 32 + quad * 8 + j) * 34 + mtile * 16 + l16];
                ushort h = f2bu(v);
                ah[j] = (short)h;
                al[j] = (short)f2bu(v - bu2f(h));
            }
#pragma unroll
            for (int nti = 0; nti < 2; ++nti) {
                const int boff = ((kb * 4 + nt0 + nti) * 512) + ln * 8;
                short8 wh = *(const short8*)(Wlin + 8192 + boff);
                short8 wl = *(const short8*)(Wlin + 12288 + boff);
                lacc[nti] = __builtin_amdgcn_mfma_f32_16x16x32_bf16(ah, wh, lacc[nti], 0, 0, 0);
                lacc[nti] = __builtin_amdgcn_mfma_f32_16x16x32_bf16(al, wh, lacc[nti], 0, 0, 0);
                lacc[nti] = __builtin_amdgcn_mfma_f32_16x16x32_bf16(ah, wl, lacc[nti], 0, 0, 0);
            }
        }
        __syncthreads();
#pragma unroll
        for (int nti = 0; nti < 2; ++nti) {
            int o = (nt0 + nti) * 16 + l16;
#pragma unroll
            for (int r = 0; r < 4; ++r)
                hsf[o * 34 + mtile * 16 + quad * 4 + r] = fmaxf(lacc[nti][r] + B2V(o), 0.f);
        }
    }
    __syncthreads();

    // ---- write XHout (bf16) from hsf ----
    if (XHout) {
#pragma unroll
        for (int ni = 0; ni < 2; ++ni) {
            int n = n0 + ni;
            int node = pnod[n];
            if (node >= 0) {
                ushort4 h;
                h.x = f2bu(hsf[(o0 + 0) * 34 + n]);
                h.y = f2bu(hsf[(o0 + 1) * 34 + n]);
                h.z = f2bu(hsf[(o0 + 2) * 34 + n]);
                h.w = f2bu(hsf[(o0 + 3) * 34 + n]);
                *(ushort4*)(XHout + (size_t)node * DD + o0) = h;
            }
        }
    }

    // ---- BN partial sums (raw pre-BN y) + fused raw pool (identity order only) ----
    if (tid < 64) {
        float s = 0.f, sq = 0.f;
        float pacc = 0.f;
        int curg = ibatch[0];
        int lim = NN - node0;
        if (lim > 32) lim = 32;
        for (int n = 0; n < lim; ++n) {
            float v = hsf[tid * 34 + n];
            s += v;
            sq += v * v;
            if (do_pool) {
                int g = ibatch[n];
                if (g != curg) {
                    atomicAdd(&gpool[(size_t)curg * DD + tid], pacc);
                    pacc = 0.f;
                    curg = g;
                }
                pacc += v;
            }
        }
        if (do_pool && curg >= 0)
            atomicAdd(&gpool[(size_t)curg * DD + tid], pacc);
        atomicAdd(&bnstat[tid], s);
        atomicAdd(&bnstat[64 + tid], sq);
    }
}

// ---------------- head: BN3-affine on raw pool, fc1+relu, fc2, log_softmax ----------
__global__ __launch_bounds__(256) void k_head(const float* __restrict__ gpool,
                                              const float* __restrict__ bs3,
                                              const float* __restrict__ g3,
                                              const float* __restrict__ b3,
                                              const int* __restrict__ gcnt,
                                              const float* __restrict__ fc1W, const float* __restrict__ fc1b,
                                              const float* __restrict__ fc2W, const float* __restrict__ fc2b,
                                              float* __restrict__ out) {
    __shared__ float sh[12640];
    float* const gs = sh;
    float* const w1t = sh + 4096;
    float* const z1s = sh + 8256;
    float* const b1s = sh + 12416;
    float* const b2s = sh + 12480;
    float* const sc3 = sh + 12512;
    float* const shf3 = sh + 12576;
    float* const w2t = sh;
    float* const z2s = sh + 4096;

    int tid = threadIdx.x;
    if (tid < 64) {
        float mean = bs3[tid] * (1.f / NN);
        float var = fmaxf(bs3[64 + tid] * (1.f / NN) - mean * mean, 0.f);
        float inv = rsqrtf(var + BN_EPS_F);
        float A = g3[tid] * inv;
        sc3[tid] = A;
        shf3[tid] = b3[tid] - mean * A;
    }
    __syncthreads();
    for (int i = tid; i < 4096; i += 256) {
        int o = i >> 6, j = i & 63;
        gs[i] = sc3[j] * gpool[i] + shf3[j] * (float)gcnt[o];
        w1t[j * 65 + o] = fc1W[i];
    }
    if (tid < 64) b1s[tid] = fc1b[tid];
    if (tid < 32) b2s[tid] = fc2b[tid];
    __syncthreads();
    {
        int tx = tid & 15, ty = tid >> 4, o0 = tx * 4, g0 = ty * 4;
        float acc[16];
#pragma unroll
        for (int i = 0; i < 16; ++i) acc[i] = 0.f;
        for (int j = 0; j < 64; ++j) {
            float w0 = w1t[j * 65 + o0 + 0], w1 = w1t[j * 65 + o0 + 1];
            float w2 = w1t[j * 65 + o0 + 2], w3 = w1t[j * 65 + o0 + 3];
#pragma unroll
            for (int gi = 0; gi < 4; ++gi) {
                float a = gs[(g0 + gi) * 64 + j];
                acc[gi * 4 + 0] += a * w0; acc[gi * 4 + 1] += a * w1;
                acc[gi * 4 + 2] += a * w2; acc[gi * 4 + 3] += a * w3;
            }
        }
        __syncthreads();
#pragma unroll
        for (int gi = 0; gi < 4; ++gi)
#pragma unroll
            for (int oi = 0; oi < 4; ++oi)
                z1s[(g0 + gi) * 65 + o0 + oi] = fmaxf(acc[gi * 4 + oi] + b1s[o0 + oi], 0.f);
    }
    for (int i = tid; i < 2048; i += 256) {
        int o = i >> 6, j = i & 63;
        w2t[j * 33 + o] = fc2W[i];
    }
    __syncthreads();
    {
        int tx = tid & 7, ty = tid >> 3, o0 = tx * 4, g0 = ty * 2;
        float acc[8];
#pragma unroll
        for (int i = 0; i < 8; ++i) acc[i] = 0.f;
        for (int j = 0; j < 64; ++j) {
            float w0 = w2t[j * 33 + o0 + 0], w1 = w2t[j * 33 + o0 + 1];
            float w2 = w2t[j * 33 + o0 + 2], w3 = w2t[j * 33 + o0 + 3];
            float a0 = z1s[(g0 + 0) * 65 + j];
            float a1 = z1s[(g0 + 1) * 65 + j];
            acc[0] += a0 * w0; acc[1] += a0 * w1; acc[2] += a0 * w2; acc[3] += a0 * w3;
            acc[4] += a1 * w0; acc[5] += a1 * w1; acc[6] += a1 * w2; acc[7] += a1 * w3;
        }
#pragma unroll
        for (int gi = 0; gi < 2; ++gi)
#pragma unroll
            for (int oi = 0; oi < 4; ++oi)
                z2s[(g0 + gi) * 33 + o0 + oi] = acc[gi * 4 + oi] + b2s[o0 + oi];
    }
    __syncthreads();
    if (tid < 64) {
        float m = -3.402823466e38f;
        for (int c = 0; c < DOUT; ++c) m = fmaxf(m, z2s[tid * 33 + c]);
        float s = 0.f;
        for (int c = 0; c < DOUT; ++c) s += expf(z2s[tid * 33 + c] - m);
        float lse = m + logf(s);
        for (int c = 0; c < DOUT; ++c)
            out[tid * DOUT + c] = z2s[tid * 33 + c] - lse;
    }
}

extern "C" void kernel_launch(void* const* d_in, const int* in_sizes, int n_in,
                              void* d_out, int out_size, void* d_ws, size_t ws_size,
                              hipStream_t stream) {
    const float* x = (const float*)d_in[0];
    const int* ei = (const int*)d_in[1];
    const int* src = ei;
    const int* dst = ei + NE;
    const int* batch = (const int*)d_in[2];
    const float *mlpW[3], *mlpB[3], *w1[3], *bb1[3], *w2[3], *bb2[3], *bng[3], *bnb[3];
    for (int l = 0; l < 3; ++l) {
        mlpW[l] = (const float*)d_in[3 + 6 * l];
        mlpB[l] = (const float*)d_in[4 + 6 * l];
        w1[l]   = (const float*)d_in[5 + 6 * l];
        bb1[l]  = (const float*)d_in[6 + 6 * l];
        w2[l]   = (const float*)d_in[7 + 6 * l];
        bb2[l]  = (const float*)d_in[8 + 6 * l];
        bng[l]  = (const float*)d_in[21 + 2 * l];
        bnb[l]  = (const float*)d_in[22 + 2 * l];
    }
    const float* fc1W = (const float*)d_in[27];
    const float* fc1b = (const float*)d_in[28];
    const float* fc2W = (const float*)d_in[29];
    const float* fc2b = (const float*)d_in[30];
    float* out = (float*)d_out;

    char* ws = (char*)d_ws;
    size_t off = 0;
    auto alloc = [&](size_t bytes) -> void* {
        void* p = ws + off;
        off = (off + bytes + 511) & ~(size_t)511;
        return p;
    };
    int* counts    = (int*)alloc((size_t)NN * 4);
    int* row_ptr   = (int*)alloc((size_t)(NN + 1) * 4);
    int* rank      = (int*)alloc((size_t)NE * 4);
    int* blockSums = (int*)alloc(256 * 4);
    int* blockBase = (int*)alloc(256 * 4);
    int* csr_src   = (int*)alloc((size_t)NE * 4);
    int* blockHist = (int*)alloc((size_t)196 * 256 * 4);
    int* binTot    = (int*)alloc(256 * 4);
    int* perm      = (int*)alloc((size_t)NN * 4);
    ushort* XHA    = (ushort*)alloc((size_t)NN * DD * 2);
    ushort* XHB    = (ushort*)alloc((size_t)NN * DD * 2);
    ushort* Wb     = (ushort*)alloc((size_t)3 * 65536 * 2);
    ushort* Wsb    = (ushort*)alloc((size_t)3 * 16384 * 2);
    float* bnstat  = (float*)alloc(384 * 4);
    float* gpool   = (float*)alloc((size_t)NGRAPH * DD * 4);
    int* gcnt      = (int*)alloc(NGRAPH * 4);
    (void)ws_size; (void)in_sizes; (void)n_in; (void)out_size;

    k_prep<<<3125, 256, 0, stream>>>(x, XHA,
                                     mlpW[0], mlpW[1], mlpW[2],
                                     w1[0], w2[0], w1[1], w2[1], w1[2], w2[2],
                                     Wb, Wsb, counts, bnstat, gpool);
    k_rank<<<1563, 256, 0, stream>>>(dst, counts, rank);
    k_scan_a<<<196, 256, 0, stream>>>(counts, blockSums, blockHist);
    k_scanB2<<<257, 256, 0, stream>>>(blockHist, binTot, blockSums, blockBase, batch, gcnt);
    k_scanC2<<<196, 256, 0, stream>>>(counts, blockBase, row_ptr, blockHist, binTot, perm);
    k_place<<<1563, 256, 0, stream>>>(src, dst, rank, row_ptr, csr_src);

    // layer 1: perm order, in XHA (identity affine), out XHB (raw bf16 y)
    k_fused<<<1563, 256, 0, stream>>>(XHA, XHB, perm, row_ptr, csr_src,
                                      Wb, Wsb, mlpB[0], bb1[0], bb2[0],
                                      nullptr, nullptr, nullptr,
                                      bnstat, batch, gpool, 0);
    // layer 2: perm order, in XHB (affine from bnstat[0]), out XHA
    k_fused<<<1563, 256, 0, stream>>>(XHB, XHA, perm, row_ptr, csr_src,
                                      Wb + 65536, Wsb + 16384, mlpB[1], bb1[1], bb2[1],
                                      bnstat, bng[0], bnb[0],
                                      bnstat + 128, batch, gpool, 0);
    // layer 3: IDENTITY order (batch-sorted) + fused raw pool; no XH write
    k_fused<<<1563, 256, 0, stream>>>(XHA, nullptr, nullptr, row_ptr, csr_src,
                                      Wb + 2 * 65536, Wsb + 2 * 16384, mlpB[2], bb1[2], bb2[2],
                                      bnstat + 128, bng[1], bnb[1],
                                      bnstat + 256, batch, gpool, 1);
    k_head<<<1, 256, 0, stream>>>(gpool, bnstat + 256, bng[2], bnb[2], gcnt,
                                  fc1W, fc1b, fc2W, fc2b, out);
}